// Round 18
// baseline (233.761 us; speedup 1.0000x reference)
//
#include <hip/hip_runtime.h>
#include <math.h>

#define N1T 65536
#define N2T 16384
#define BSZ 8
#define N1B 8192   // points per batch in xyz1
#define N2B 2048   // points per batch in xyz2
#define C1 256
#define C2 512
#define K1 768     // C1 + C2
#define HID 256
#define BN_EPS 1e-5f

typedef short bf16x8 __attribute__((ext_vector_type(8)));
typedef float f32x4 __attribute__((ext_vector_type(4)));

// Exact single-rounded f32 ops via ISA — immune to -ffast-math / contraction.
__device__ __forceinline__ float mul_rn(float a, float b) {
    float r; asm("v_mul_f32 %0, %1, %2" : "=v"(r) : "v"(a), "v"(b)); return r;
}
__device__ __forceinline__ float add_rn(float a, float b) {
    float r; asm("v_add_f32 %0, %1, %2" : "=v"(r) : "v"(a), "v"(b)); return r;
}
__device__ __forceinline__ float sub_rn(float a, float b) {
    float r; asm("v_sub_f32 %0, %1, %2" : "=v"(r) : "v"(a), "v"(b)); return r;
}
__device__ __forceinline__ float fma_rn(float a, float b, float c) {
    float r; asm("v_fma_f32 %0, %1, %2, %3" : "=v"(r) : "v"(a), "v"(b), "v"(c)); return r;
}
// f32 -> bf16 round-to-nearest-even
__device__ __forceinline__ short f2bf(float f) {
    unsigned u = __builtin_bit_cast(unsigned, f);
    u += 0x7fffu + ((u >> 16) & 1u);
    return (short)(u >> 16);
}
// bf16 -> f32 (exact)
__device__ __forceinline__ float bf2f(short s) {
    return __builtin_bit_cast(float, ((unsigned)(unsigned short)s) << 16);
}

// ---------------------------------------------------------------- KNN-3
// FROZEN: r13's kernel verbatim — best measured (72.3 µs).
__global__ __launch_bounds__(256) void knn_kernel(
    const float* __restrict__ xyz1, const float* __restrict__ xyz2,
    int* __restrict__ idx_out, float* __restrict__ w_out)
{
    __shared__ float4 sref[N2B + 4];         // padded: pos = p + p/512
    const int tid = threadIdx.x;
    const int qbase = blockIdx.x * 64;       // 1024 blocks x 64 queries
    const int batch = qbase / N1B;
    const float* k2 = xyz2 + (size_t)batch * N2B * 3;
    for (int p = tid; p < N2B; p += 256) {
        float x = k2[3 * p], y = k2[3 * p + 1], z = k2[3 * p + 2];
        float kk = add_rn(add_rn(mul_rn(x, x), mul_rn(y, y)), mul_rn(z, z));
        sref[p + (p >> 9)] = make_float4(x, y, z, kk);
    }
    __syncthreads();

    const int q = qbase + (tid >> 2);
    const int sub = tid & 3;
    const float qx = xyz1[q * 3 + 0], qy = xyz1[q * 3 + 1], qz = xyz1[q * 3 + 2];
    const float qq = add_rn(add_rn(mul_rn(qx, qx), mul_rn(qy, qy)), mul_rn(qz, qz));

    const int base = sub * 513;              // padded LDS base
    const int gbase = sub * 512;             // global index base
    float a0 = 1e30f, a1 = 1e30f, a2 = 1e30f;
    int   ai0 = 0x7fffffff, ai1 = 0x7fffffff, ai2 = 0x7fffffff;
    float c0 = 1e30f, c1 = 1e30f, c2 = 1e30f;
    int   ci0 = 0x7fffffff, ci1 = 0x7fffffff, ci2 = 0x7fffffff;
    for (int jj = 0; jj < 256; ++jj) {
        float4 rA = sref[base + jj];
        float4 rB = sref[base + 256 + jj];
        float pA = mul_rn(qx, rA.x);
        float tA = fma_rn(qz, rA.z, fma_rn(qy, rA.y, pA));
        float dA = add_rn(sub_rn(qq, add_rn(tA, tA)), rA.w);
        float pB = mul_rn(qx, rB.x);
        float tB = fma_rn(qz, rB.z, fma_rn(qy, rB.y, pB));
        float dB = add_rn(sub_rn(qq, add_rn(tB, tB)), rB.w);
        if (dA < a2) {
            if (dA < a1) {
                a2 = a1; ai2 = ai1;
                if (dA < a0) { a1 = a0; ai1 = ai0; a0 = dA; ai0 = gbase + jj; }
                else         { a1 = dA; ai1 = gbase + jj; }
            } else { a2 = dA; ai2 = gbase + jj; }
        }
        if (dB < c2) {
            if (dB < c1) {
                c2 = c1; ci2 = ci1;
                if (dB < c0) { c1 = c0; ci1 = ci0; c0 = dB; ci0 = gbase + 256 + jj; }
                else         { c1 = dB; ci1 = gbase + 256 + jj; }
            } else { c2 = dB; ci2 = gbase + 256 + jj; }
        }
    }
    float bd0 = a0, bd1 = a1, bd2 = a2;
    int   bi0 = ai0, bi1 = ai1, bi2 = ai2;
#define LEXINS(d, ji)                                                        \
    if ((d < bd2) || (d == bd2 && ji < bi2)) {                               \
        if ((d < bd1) || (d == bd1 && ji < bi1)) {                           \
            bd2 = bd1; bi2 = bi1;                                            \
            if ((d < bd0) || (d == bd0 && ji < bi0)) {                       \
                bd1 = bd0; bi1 = bi0; bd0 = d; bi0 = ji;                     \
            } else { bd1 = d; bi1 = ji; }                                    \
        } else { bd2 = d; bi2 = ji; }                                        \
    }
    LEXINS(c0, ci0) LEXINS(c1, ci1) LEXINS(c2, ci2)
#pragma unroll
    for (int mask = 1; mask <= 2; mask <<= 1) {
        float pd0 = __shfl_xor(bd0, mask, 64);
        float pd1 = __shfl_xor(bd1, mask, 64);
        float pd2 = __shfl_xor(bd2, mask, 64);
        int   pi0 = __shfl_xor(bi0, mask, 64);
        int   pi1 = __shfl_xor(bi1, mask, 64);
        int   pi2 = __shfl_xor(bi2, mask, 64);
        LEXINS(pd0, pi0) LEXINS(pd1, pi1) LEXINS(pd2, pi2)
    }
#undef LEXINS
    if (sub == 0) {
        float d0s = __fsqrt_rn(fmaxf(bd0, 0.0f));
        float d1s = __fsqrt_rn(fmaxf(bd1, 0.0f));
        float d2s = __fsqrt_rn(fmaxf(bd2, 0.0f));
        float r0 = __fdiv_rn(1.0f, add_rn(d0s, 1e-8f));
        float r1 = __fdiv_rn(1.0f, add_rn(d1s, 1e-8f));
        float r2 = __fdiv_rn(1.0f, add_rn(d2s, 1e-8f));
        float rs = add_rn(add_rn(r0, r1), r2);
        w_out[q * 3 + 0] = __fdiv_rn(r0, rs);
        w_out[q * 3 + 1] = __fdiv_rn(r1, rs);
        w_out[q * 3 + 2] = __fdiv_rn(r2, rs);
        idx_out[q * 3 + 0] = batch * N2B + bi0;
        idx_out[q * 3 + 1] = batch * N2B + bi1;
        idx_out[q * 3 + 2] = batch * N2B + bi2;
    }
}

// ------------------------------------------------------ prep kernels
__global__ __launch_bounds__(256) void cast_p2_kernel(
    const float* __restrict__ p2, short* __restrict__ p2b)
{
    const size_t i = ((size_t)blockIdx.x * 256 + threadIdx.x) * 8;
    float4 u0 = *(const float4*)(p2 + i);
    float4 u1 = *(const float4*)(p2 + i + 4);
    bf16x8 v;
    v[0] = f2bf(u0.x); v[1] = f2bf(u0.y); v[2] = f2bf(u0.z); v[3] = f2bf(u0.w);
    v[4] = f2bf(u1.x); v[5] = f2bf(u1.y); v[6] = f2bf(u1.z); v[7] = f2bf(u1.w);
    *(bf16x8*)(p2b + i) = v;
}

// W1[768][256] f32 -> w1at[256][256] bf16 (k<256), w1bt[256][512] bf16 (k>=256)
__global__ __launch_bounds__(256) void transpose_w1_kernel(
    const float* __restrict__ W1, short* __restrict__ w1at, short* __restrict__ w1bt)
{
    const int e = blockIdx.x * 256 + threadIdx.x;   // over 768*256
    const int k = e / HID, n = e % HID;
    short v = f2bf(W1[e]);
    if (k < C1) w1at[(size_t)n * C1 + k] = v;
    else        w1bt[(size_t)n * C2 + (k - C1)] = v;
}

// W[K][N] f32 -> WT[N][K] bf16
__global__ __launch_bounds__(256) void transpose_w_kernel(
    const float* __restrict__ Win, short* __restrict__ WT, int K, int N)
{
    const int e = blockIdx.x * 256 + threadIdx.x;
    const int k = e / N, n = e % N;
    WT[(size_t)n * K + k] = f2bf(Win[e]);
}

// --------------------------------------------- bf16 MFMA GEMMs
#define LDP 40

// ============ zgemm: Z[16384][256] = p2b @ W1b  (f32 out, no bias) =========
__global__ __launch_bounds__(256) void zgemm_kernel(
    const short* __restrict__ p2b, const short* __restrict__ w1bt,
    float* __restrict__ Z)
{
    __shared__ short As[128][LDP];
    __shared__ short Bs[128][LDP];
    const int tid = threadIdx.x;
    const int lane = tid & 63, wv = tid >> 6;
    const int wr = wv >> 1, wc = wv & 1;
    const int l16 = lane & 15, kh = (lane >> 4) * 8;
    const int row0 = blockIdx.y * 128, col0 = blockIdx.x * 128;
    f32x4 acc[4][4];
#pragma unroll
    for (int m = 0; m < 4; ++m)
#pragma unroll
        for (int n = 0; n < 4; ++n) acc[m][n] = (f32x4){0.f, 0.f, 0.f, 0.f};

    const int c0 = tid * 2;
    const int r0c = c0 >> 2, kc0 = (c0 & 3) * 8;
    const int r1c = (c0 + 1) >> 2, kc1 = ((c0 + 1) & 3) * 8;

    for (int kt = 0; kt < C2 / 32; ++kt) {
        const int k0 = kt * 32;
        bf16x8 va = *(const bf16x8*)(p2b + (size_t)(row0 + r0c) * C2 + k0 + kc0);
        bf16x8 vb = *(const bf16x8*)(p2b + (size_t)(row0 + r1c) * C2 + k0 + kc1);
        bf16x8 wa = *(const bf16x8*)(w1bt + (size_t)(col0 + r0c) * C2 + k0 + kc0);
        bf16x8 wb = *(const bf16x8*)(w1bt + (size_t)(col0 + r1c) * C2 + k0 + kc1);
        __syncthreads();
        *(bf16x8*)(&As[r0c][kc0]) = va;
        *(bf16x8*)(&As[r1c][kc1]) = vb;
        *(bf16x8*)(&Bs[r0c][kc0]) = wa;
        *(bf16x8*)(&Bs[r1c][kc1]) = wb;
        __syncthreads();

        bf16x8 af[4], bf[4];
#pragma unroll
        for (int m = 0; m < 4; ++m)
            af[m] = *(const bf16x8*)(&As[wr * 64 + m * 16 + l16][kh]);
#pragma unroll
        for (int n = 0; n < 4; ++n)
            bf[n] = *(const bf16x8*)(&Bs[wc * 64 + n * 16 + l16][kh]);
#pragma unroll
        for (int m = 0; m < 4; ++m)
#pragma unroll
            for (int n = 0; n < 4; ++n)
                acc[m][n] = __builtin_amdgcn_mfma_f32_16x16x32_bf16(
                    af[m], bf[n], acc[m][n], 0, 0, 0);
    }
#pragma unroll
    for (int n = 0; n < 4; ++n) {
        const int col = col0 + wc * 64 + n * 16 + l16;
#pragma unroll
        for (int m = 0; m < 4; ++m) {
            const int rowb = row0 + wr * 64 + m * 16 + (lane >> 4) * 4;
#pragma unroll
            for (int j = 0; j < 4; ++j)
                Z[(size_t)(rowb + j) * HID + col] = acc[m][n][j];
        }
    }
}

// ============ gemm1m: y1 = P1 @ W1a + IDW(Z) + b1  (8-wave 128x256) ========
// K-loop only over C1=256 (8 iters). Epilogue gathers 3 Z-rows per output
// row (L2-resident) and adds the IDW combination — exact-linear rewrite of
// interp @ W1b. BN stats from final f32 values.
__global__ __launch_bounds__(512) void gemm1m_kernel(
    const float* __restrict__ points1, const float* __restrict__ Z,
    const int* __restrict__ idx, const float* __restrict__ w,
    const short* __restrict__ w1at, const float* __restrict__ bias,
    short* __restrict__ y1b, float* __restrict__ psum, float* __restrict__ psq)
{
    __shared__ short As[128][LDP];
    __shared__ short Bs[256][LDP];
    __shared__ int   sidx[128][3];
    __shared__ float swt[128][3];
    __shared__ float redS[2][4][64], redQ[2][4][64];
    const int tid = threadIdx.x;              // 0..511
    const int lane = tid & 63, wv = tid >> 6; // 8 waves
    const int wr = wv >> 2, wc = wv & 3;      // 2 x 4 wave grid (64x64 each)
    const int l16 = lane & 15, kh = (lane >> 4) * 8;
    const int row0 = blockIdx.x * 128;

    if (tid < 128) {
        sidx[tid][0] = idx[(row0 + tid) * 3 + 0];
        sidx[tid][1] = idx[(row0 + tid) * 3 + 1];
        sidx[tid][2] = idx[(row0 + tid) * 3 + 2];
        swt[tid][0] = w[(row0 + tid) * 3 + 0];
        swt[tid][1] = w[(row0 + tid) * 3 + 1];
        swt[tid][2] = w[(row0 + tid) * 3 + 2];
    }

    f32x4 acc[4][4];
#pragma unroll
    for (int m = 0; m < 4; ++m)
#pragma unroll
        for (int n = 0; n < 4; ++n) acc[m][n] = (f32x4){0.f, 0.f, 0.f, 0.f};

    const int arow = tid >> 2, akc = (tid & 3) * 8;
    const int rowA = row0 + arow;
    const int cb0 = tid * 2, cb1 = tid * 2 + 1;
    const int brow0 = cb0 >> 2, bkc0 = (cb0 & 3) * 8;
    const int brow1 = cb1 >> 2, bkc1 = (cb1 & 3) * 8;

#define LOAD_A(VA, KT)                                                        \
    {                                                                         \
        const int k0_ = (KT) * 32;                                            \
        float4 u0 = *(const float4*)(points1 + (size_t)rowA * C1 + k0_ + akc);     \
        float4 u1 = *(const float4*)(points1 + (size_t)rowA * C1 + k0_ + akc + 4); \
        VA[0] = f2bf(u0.x); VA[1] = f2bf(u0.y); VA[2] = f2bf(u0.z); VA[3] = f2bf(u0.w); \
        VA[4] = f2bf(u1.x); VA[5] = f2bf(u1.y); VA[6] = f2bf(u1.z); VA[7] = f2bf(u1.w); \
    }
#define LOAD_B(WA, WB, KT)                                                    \
    {                                                                         \
        const int k0_ = (KT) * 32;                                            \
        WA = *(const bf16x8*)(w1at + (size_t)brow0 * C1 + k0_ + bkc0);        \
        WB = *(const bf16x8*)(w1at + (size_t)brow1 * C1 + k0_ + bkc1);        \
    }

    bf16x8 va, wa, wb;
    LOAD_A(va, 0)
    LOAD_B(wa, wb, 0)
    for (int kt = 0; kt < C1 / 32; ++kt) {
        __syncthreads();
        *(bf16x8*)(&As[arow][akc]) = va;
        *(bf16x8*)(&Bs[brow0][bkc0]) = wa;
        *(bf16x8*)(&Bs[brow1][bkc1]) = wb;
        __syncthreads();
        if (kt + 1 < C1 / 32) {
            LOAD_A(va, kt + 1)
            LOAD_B(wa, wb, kt + 1)
        }
        bf16x8 af[4], bf[4];
#pragma unroll
        for (int m = 0; m < 4; ++m)
            af[m] = *(const bf16x8*)(&As[wr * 64 + m * 16 + l16][kh]);
#pragma unroll
        for (int n = 0; n < 4; ++n)
            bf[n] = *(const bf16x8*)(&Bs[wc * 64 + n * 16 + l16][kh]);
#pragma unroll
        for (int m = 0; m < 4; ++m)
#pragma unroll
            for (int n = 0; n < 4; ++n)
                acc[m][n] = __builtin_amdgcn_mfma_f32_16x16x32_bf16(
                    af[m], bf[n], acc[m][n], 0, 0, 0);
    }
#undef LOAD_A
#undef LOAD_B
    // epilogue: v = acc + bias + IDW(Z); store bf16; BN partials per col
    float bv[4];
#pragma unroll
    for (int n = 0; n < 4; ++n) bv[n] = bias[wc * 64 + n * 16 + l16];
    float s[4] = {0.f, 0.f, 0.f, 0.f}, qa[4] = {0.f, 0.f, 0.f, 0.f};
#pragma unroll
    for (int m = 0; m < 4; ++m) {
        const int rl0 = wr * 64 + m * 16 + (lane >> 4) * 4;
#pragma unroll
        for (int j = 0; j < 4; ++j) {
            const int rl = rl0 + j;
            const int j0 = sidx[rl][0], j1 = sidx[rl][1], j2 = sidx[rl][2];
            const float w0 = swt[rl][0], w1 = swt[rl][1], w2 = swt[rl][2];
            const float* z0 = Z + (size_t)j0 * HID;
            const float* z1 = Z + (size_t)j1 * HID;
            const float* z2 = Z + (size_t)j2 * HID;
#pragma unroll
            for (int n = 0; n < 4; ++n) {
                const int col = wc * 64 + n * 16 + l16;
                float zi = fmaf(w0, z0[col], fmaf(w1, z1[col], w2 * z2[col]));
                float v = acc[m][n][j] + bv[n] + zi;
                y1b[(size_t)(row0 + rl) * HID + col] = f2bf(v);
                s[n] += v; qa[n] = fmaf(v, v, qa[n]);
            }
        }
    }
#pragma unroll
    for (int n = 0; n < 4; ++n) {
        float sv = s[n], qv = qa[n];
        sv += __shfl_xor(sv, 16, 64);  sv += __shfl_xor(sv, 32, 64);
        qv += __shfl_xor(qv, 16, 64);  qv += __shfl_xor(qv, 32, 64);
        if ((lane >> 4) == 0) {
            redS[wr][wc][n * 16 + l16] = sv;
            redQ[wr][wc][n * 16 + l16] = qv;
        }
    }
    __syncthreads();
    if (tid < 256) {
        const int wcf = tid >> 6, cf = tid & 63;
        float sv = redS[0][wcf][cf] + redS[1][wcf][cf];
        float qv = redQ[0][wcf][cf] + redQ[1][wcf][cf];
        psum[(size_t)blockIdx.x * HID + tid] = sv;
        psq[(size_t)blockIdx.x * HID + tid] = qv;
    }
}

// ============ gemm2m: unchanged r16/r17 structure (128x128, 4 waves) =======
#define GEMM_EPILOGUE(STORE_STMT)                                             \
    __shared__ float redS[2][2][64], redQ[2][2][64];                          \
    _Pragma("unroll")                                                         \
    for (int n = 0; n < 4; ++n) {                                             \
        const int col = col0 + wc * 64 + n * 16 + l16;                        \
        const float bv = bias[col];                                           \
        float s = 0.f, qa = 0.f;                                              \
        _Pragma("unroll")                                                     \
        for (int m = 0; m < 4; ++m) {                                         \
            const int rowb = row0 + wr * 64 + m * 16 + (lane >> 4) * 4;       \
            _Pragma("unroll")                                                 \
            for (int j = 0; j < 4; ++j) {                                     \
                float v = acc[m][n][j] + bv;                                  \
                STORE_STMT;                                                   \
                s += v; qa = fmaf(v, v, qa);                                  \
            }                                                                 \
        }                                                                     \
        s += __shfl_xor(s, 16, 64);  s += __shfl_xor(s, 32, 64);              \
        qa += __shfl_xor(qa, 16, 64); qa += __shfl_xor(qa, 32, 64);           \
        if ((lane >> 4) == 0) {                                               \
            redS[wr][wc][n * 16 + l16] = s;                                   \
            redQ[wr][wc][n * 16 + l16] = qa;                                  \
        }                                                                     \
    }                                                                         \
    __syncthreads();                                                          \
    if (tid < 128) {                                                          \
        const int wcf = tid >> 6, cf = tid & 63;                              \
        float s = redS[0][wcf][cf] + redS[1][wcf][cf];                        \
        float qa = redQ[0][wcf][cf] + redQ[1][wcf][cf];                       \
        const int gcol = col0 + wcf * 64 + cf;                                \
        psum[(size_t)blockIdx.y * HID + gcol] = s;                            \
        psq[(size_t)blockIdx.y * HID + gcol] = qa;                            \
    }

// y2b = bf16( relu(bn(y1b)) @ W2 + b2 ), stats from f32 acc
__global__ __launch_bounds__(256) void gemm2m_kernel(
    const short* __restrict__ y1b, const float* __restrict__ scale,
    const float* __restrict__ shift, const short* __restrict__ w2t,
    const float* __restrict__ bias, short* __restrict__ y2b,
    float* __restrict__ psum, float* __restrict__ psq)
{
    __shared__ short As[128][LDP];
    __shared__ short Bs[128][LDP];
    const int tid = threadIdx.x;
    const int lane = tid & 63, wv = tid >> 6;
    const int wr = wv >> 1, wc = wv & 1;
    const int l16 = lane & 15, kh = (lane >> 4) * 8;
    const int row0 = blockIdx.y * 128, col0 = blockIdx.x * 128;
    f32x4 acc[4][4];
#pragma unroll
    for (int m = 0; m < 4; ++m)
#pragma unroll
        for (int n = 0; n < 4; ++n) acc[m][n] = (f32x4){0.f, 0.f, 0.f, 0.f};

    const int c0 = tid * 2;
    const int r0c = c0 >> 2, kc0 = (c0 & 3) * 8;
    const int r1c = (c0 + 1) >> 2, kc1 = ((c0 + 1) & 3) * 8;

    for (int kt = 0; kt < HID / 32; ++kt) {
        const int k0 = kt * 32;
        bf16x8 x0 = *(const bf16x8*)(y1b + (size_t)(row0 + r0c) * HID + k0 + kc0);
        bf16x8 x1 = *(const bf16x8*)(y1b + (size_t)(row0 + r1c) * HID + k0 + kc1);
        float4 s0 = *(const float4*)(scale + k0 + kc0);
        float4 s1 = *(const float4*)(scale + k0 + kc0 + 4);
        float4 h0 = *(const float4*)(shift + k0 + kc0);
        float4 h1 = *(const float4*)(shift + k0 + kc0 + 4);
        float4 s2 = *(const float4*)(scale + k0 + kc1);
        float4 s3 = *(const float4*)(scale + k0 + kc1 + 4);
        float4 h2 = *(const float4*)(shift + k0 + kc1);
        float4 h3 = *(const float4*)(shift + k0 + kc1 + 4);
        bf16x8 va, vb;
        va[0] = f2bf(fmaxf(fmaf(bf2f(x0[0]), s0.x, h0.x), 0.f));
        va[1] = f2bf(fmaxf(fmaf(bf2f(x0[1]), s0.y, h0.y), 0.f));
        va[2] = f2bf(fmaxf(fmaf(bf2f(x0[2]), s0.z, h0.z), 0.f));
        va[3] = f2bf(fmaxf(fmaf(bf2f(x0[3]), s0.w, h0.w), 0.f));
        va[4] = f2bf(fmaxf(fmaf(bf2f(x0[4]), s1.x, h1.x), 0.f));
        va[5] = f2bf(fmaxf(fmaf(bf2f(x0[5]), s1.y, h1.y), 0.f));
        va[6] = f2bf(fmaxf(fmaf(bf2f(x0[6]), s1.z, h1.z), 0.f));
        va[7] = f2bf(fmaxf(fmaf(bf2f(x0[7]), s1.w, h1.w), 0.f));
        vb[0] = f2bf(fmaxf(fmaf(bf2f(x1[0]), s2.x, h2.x), 0.f));
        vb[1] = f2bf(fmaxf(fmaf(bf2f(x1[1]), s2.y, h2.y), 0.f));
        vb[2] = f2bf(fmaxf(fmaf(bf2f(x1[2]), s2.z, h2.z), 0.f));
        vb[3] = f2bf(fmaxf(fmaf(bf2f(x1[3]), s2.w, h2.w), 0.f));
        vb[4] = f2bf(fmaxf(fmaf(bf2f(x1[4]), s3.x, h3.x), 0.f));
        vb[5] = f2bf(fmaxf(fmaf(bf2f(x1[5]), s3.y, h3.y), 0.f));
        vb[6] = f2bf(fmaxf(fmaf(bf2f(x1[6]), s3.z, h3.z), 0.f));
        vb[7] = f2bf(fmaxf(fmaf(bf2f(x1[7]), s3.w, h3.w), 0.f));
        bf16x8 wa = *(const bf16x8*)(w2t + (size_t)(col0 + r0c) * HID + k0 + kc0);
        bf16x8 wb = *(const bf16x8*)(w2t + (size_t)(col0 + r1c) * HID + k0 + kc1);
        __syncthreads();
        *(bf16x8*)(&As[r0c][kc0]) = va;
        *(bf16x8*)(&As[r1c][kc1]) = vb;
        *(bf16x8*)(&Bs[r0c][kc0]) = wa;
        *(bf16x8*)(&Bs[r1c][kc1]) = wb;
        __syncthreads();

        bf16x8 af[4], bf[4];
#pragma unroll
        for (int m = 0; m < 4; ++m)
            af[m] = *(const bf16x8*)(&As[wr * 64 + m * 16 + l16][kh]);
#pragma unroll
        for (int n = 0; n < 4; ++n)
            bf[n] = *(const bf16x8*)(&Bs[wc * 64 + n * 16 + l16][kh]);
#pragma unroll
        for (int m = 0; m < 4; ++m)
#pragma unroll
            for (int n = 0; n < 4; ++n)
                acc[m][n] = __builtin_amdgcn_mfma_f32_16x16x32_bf16(
                    af[m], bf[n], acc[m][n], 0, 0, 0);
    }
    GEMM_EPILOGUE(y2b[(size_t)(rowb + j) * HID + col] = f2bf(v))
}

// ----------------------------------------------------- BN finalize (512 rows)
__global__ __launch_bounds__(256) void bn_finalize_kernel(
    const float* __restrict__ psum, const float* __restrict__ psq,
    const float* __restrict__ g, const float* __restrict__ be,
    float* __restrict__ scale, float* __restrict__ shift)
{
    const int c = threadIdx.x;
    float s = 0.0f, q = 0.0f;
    for (int b = 0; b < 512; ++b) { s += psum[b * HID + c]; q += psq[b * HID + c]; }
    const float inv_n = 1.0f / (float)N1T;
    const float mu = s * inv_n;
    const float var = fmaxf(q * inv_n - mu * mu, 0.0f);
    const float sc = g[c] * rsqrtf(var + BN_EPS);
    scale[c] = sc;
    shift[c] = be[c] - mu * sc;
}

// --------------------------------------------------------- final BN+ReLU
__global__ __launch_bounds__(256) void bn_apply_kernel(
    const short* __restrict__ y2b, const float* __restrict__ scale,
    const float* __restrict__ shift, float* __restrict__ out)
{
    const size_t i = ((size_t)blockIdx.x * 256 + threadIdx.x) * 8;
    const int c8 = (int)(i & 255);
    bf16x8 x = *(const bf16x8*)(y2b + i);
    float4 s0 = *(const float4*)(scale + c8);
    float4 s1 = *(const float4*)(scale + c8 + 4);
    float4 h0 = *(const float4*)(shift + c8);
    float4 h1 = *(const float4*)(shift + c8 + 4);
    float4 o0, o1;
    o0.x = fmaxf(fmaf(bf2f(x[0]), s0.x, h0.x), 0.f);
    o0.y = fmaxf(fmaf(bf2f(x[1]), s0.y, h0.y), 0.f);
    o0.z = fmaxf(fmaf(bf2f(x[2]), s0.z, h0.z), 0.f);
    o0.w = fmaxf(fmaf(bf2f(x[3]), s0.w, h0.w), 0.f);
    o1.x = fmaxf(fmaf(bf2f(x[4]), s1.x, h1.x), 0.f);
    o1.y = fmaxf(fmaf(bf2f(x[5]), s1.y, h1.y), 0.f);
    o1.z = fmaxf(fmaf(bf2f(x[6]), s1.z, h1.z), 0.f);
    o1.w = fmaxf(fmaf(bf2f(x[7]), s1.w, h1.w), 0.f);
    *(float4*)(out + i) = o0;
    *(float4*)(out + i + 4) = o1;
}

// -------------------------------------------------------------- launcher
extern "C" void kernel_launch(void* const* d_in, const int* in_sizes, int n_in,
                              void* d_out, int out_size, void* d_ws, size_t ws_size,
                              hipStream_t stream)
{
    const float* xyz1    = (const float*)d_in[0];
    const float* points1 = (const float*)d_in[1];
    const float* xyz2    = (const float*)d_in[2];
    const float* points2 = (const float*)d_in[3];
    const float* W1  = (const float*)d_in[6];
    const float* b1  = (const float*)d_in[7];
    const float* g1  = (const float*)d_in[8];
    const float* be1 = (const float*)d_in[9];
    const float* W2  = (const float*)d_in[10];
    const float* b2  = (const float*)d_in[11];
    const float* g2  = (const float*)d_in[12];
    const float* be2 = (const float*)d_in[13];
    float* out = (float*)d_out;

    char* ws = (char*)d_ws;
    short* y1b  = (short*)ws;                          // bf16 [N1][256]
    short* y2b  = (short*)(ws + 33554432);             // bf16 [N1][256]
    short* p2b  = (short*)(ws + 67108864);             // bf16 [N2T][512]
    float* Z    = (float*)(ws + 67108864 + 16777216);  // f32 [N2T][256]
    size_t off  = 67108864 + 16777216 + 16777216;
    short*  w1at   = (short*)(ws + off);  off += (size_t)C1 * HID * 2;
    short*  w1bt   = (short*)(ws + off);  off += (size_t)C2 * HID * 2;
    short*  w2t    = (short*)(ws + off);  off += (size_t)HID * HID * 2;
    int*    idx    = (int*)(ws + off);    off += (size_t)N1T * 3 * 4;
    float*  w      = (float*)(ws + off);  off += (size_t)N1T * 3 * 4;
    float*  psum   = (float*)(ws + off);  off += 512 * 256 * 4;
    float*  psq    = (float*)(ws + off);  off += 512 * 256 * 4;
    float*  scale1 = (float*)(ws + off);  off += 256 * 4;
    float*  shift1 = (float*)(ws + off);  off += 256 * 4;
    float*  scale2 = (float*)(ws + off);  off += 256 * 4;
    float*  shift2 = (float*)(ws + off);  off += 256 * 4;

    cast_p2_kernel<<<N2T * C2 / 8 / 256, 256, 0, stream>>>(points2, p2b);
    transpose_w1_kernel<<<K1 * HID / 256, 256, 0, stream>>>(W1, w1at, w1bt);
    transpose_w_kernel<<<HID * HID / 256, 256, 0, stream>>>(W2, w2t, HID, HID);
    zgemm_kernel<<<dim3(HID / 128, N2T / 128), 256, 0, stream>>>(p2b, w1bt, Z);
    knn_kernel<<<1024, 256, 0, stream>>>(xyz1, xyz2, idx, w);
    gemm1m_kernel<<<N1T / 128, 512, 0, stream>>>(
        points1, Z, idx, w, w1at, b1, y1b, psum, psq);
    bn_finalize_kernel<<<1, 256, 0, stream>>>(psum, psq, g1, be1, scale1, shift1);
    gemm2m_kernel<<<dim3(HID / 128, N1T / 128), 256, 0, stream>>>(
        y1b, scale1, shift1, w2t, b2, y2b, psum, psq);
    bn_finalize_kernel<<<1, 256, 0, stream>>>(psum, psq, g2, be2, scale2, shift2);
    bn_apply_kernel<<<N1T * HID / 8 / 256, 256, 0, stream>>>(y2b, scale2, shift2, out);
}

// Round 19
// 230.476 us; speedup vs baseline: 1.0143x; 1.0143x over previous
//
#include <hip/hip_runtime.h>
#include <math.h>

#define N1T 65536
#define N2T 16384
#define BSZ 8
#define N1B 8192   // points per batch in xyz1
#define N2B 2048   // points per batch in xyz2
#define C1 256
#define C2 512
#define K1 768     // C1 + C2
#define HID 256
#define BN_EPS 1e-5f

typedef short bf16x8 __attribute__((ext_vector_type(8)));
typedef float f32x4 __attribute__((ext_vector_type(4)));

// Exact single-rounded f32 ops via ISA — immune to -ffast-math / contraction.
__device__ __forceinline__ float mul_rn(float a, float b) {
    float r; asm("v_mul_f32 %0, %1, %2" : "=v"(r) : "v"(a), "v"(b)); return r;
}
__device__ __forceinline__ float add_rn(float a, float b) {
    float r; asm("v_add_f32 %0, %1, %2" : "=v"(r) : "v"(a), "v"(b)); return r;
}
__device__ __forceinline__ float sub_rn(float a, float b) {
    float r; asm("v_sub_f32 %0, %1, %2" : "=v"(r) : "v"(a), "v"(b)); return r;
}
__device__ __forceinline__ float fma_rn(float a, float b, float c) {
    float r; asm("v_fma_f32 %0, %1, %2, %3" : "=v"(r) : "v"(a), "v"(b), "v"(c)); return r;
}
// f32 -> bf16 round-to-nearest-even
__device__ __forceinline__ short f2bf(float f) {
    unsigned u = __builtin_bit_cast(unsigned, f);
    u += 0x7fffu + ((u >> 16) & 1u);
    return (short)(u >> 16);
}
// bf16 -> f32 (exact)
__device__ __forceinline__ float bf2f(short s) {
    return __builtin_bit_cast(float, ((unsigned)(unsigned short)s) << 16);
}

#define LDP 40

// ================= phase0: weight transposes (independent, merged) =========
// bid < 768: W1[768][256] -> w1at[256][256] (k<256), w1bt[256][512] (k>=256)
// bid >= 768: W2[256][256] -> w2t[256][256]
__global__ __launch_bounds__(256) void prep_w_kernel(
    const float* __restrict__ W1, const float* __restrict__ W2,
    short* __restrict__ w1at, short* __restrict__ w1bt, short* __restrict__ w2t)
{
    const int bid = blockIdx.x;
    if (bid < 768) {
        const int e = bid * 256 + threadIdx.x;       // over 768*256
        const int k = e / HID, n = e % HID;
        short v = f2bf(W1[e]);
        if (k < C1) w1at[(size_t)n * C1 + k] = v;
        else        w1bt[(size_t)n * C2 + (k - C1)] = v;
    } else {
        const int e = (bid - 768) * 256 + threadIdx.x; // over 256*256
        const int k = e / HID, n = e % HID;
        w2t[(size_t)n * HID + k] = f2bf(W2[e]);
    }
}

// ================= phase1: zgemm (256 blocks) + knn (1024 blocks) ==========
// Independent work co-dispatched: zgemm is MFMA-bound, knn is VALU-bound —
// separate pipes co-schedule (m114), so zgemm hides under knn.
// zgemm: Z[16384][256] = bf16(points2) @ W1b   (A cast in-flight, == p2b path)
// knn: r13's kernel verbatim (frozen, 72 µs plateau).
__global__ __launch_bounds__(256) void phase1_kernel(
    const float* __restrict__ points2, const short* __restrict__ w1bt,
    float* __restrict__ Z,
    const float* __restrict__ xyz1, const float* __restrict__ xyz2,
    int* __restrict__ idx_out, float* __restrict__ w_out)
{
    __shared__ __align__(16) char smem[32832];   // max(knn 32832, zgemm 20480)
    const int bid = blockIdx.x;
    const int tid = threadIdx.x;

    if (bid < 256) {
        // ---------------- zgemm ----------------
        short (*As)[LDP] = (short(*)[LDP])smem;
        short (*Bs)[LDP] = (short(*)[LDP])(smem + 128 * LDP * 2);
        const int lane = tid & 63, wv = tid >> 6;
        const int wr = wv >> 1, wc = wv & 1;
        const int l16 = lane & 15, kh = (lane >> 4) * 8;
        const int row0 = (bid >> 1) * 128, col0 = (bid & 1) * 128;
        f32x4 acc[4][4];
#pragma unroll
        for (int m = 0; m < 4; ++m)
#pragma unroll
            for (int n = 0; n < 4; ++n) acc[m][n] = (f32x4){0.f, 0.f, 0.f, 0.f};

        const int c0 = tid * 2;
        const int r0c = c0 >> 2, kc0 = (c0 & 3) * 8;
        const int r1c = (c0 + 1) >> 2, kc1 = ((c0 + 1) & 3) * 8;

        for (int kt = 0; kt < C2 / 32; ++kt) {
            const int k0 = kt * 32;
            float4 u0 = *(const float4*)(points2 + (size_t)(row0 + r0c) * C2 + k0 + kc0);
            float4 u1 = *(const float4*)(points2 + (size_t)(row0 + r0c) * C2 + k0 + kc0 + 4);
            float4 u2 = *(const float4*)(points2 + (size_t)(row0 + r1c) * C2 + k0 + kc1);
            float4 u3 = *(const float4*)(points2 + (size_t)(row0 + r1c) * C2 + k0 + kc1 + 4);
            bf16x8 va, vb;
            va[0] = f2bf(u0.x); va[1] = f2bf(u0.y); va[2] = f2bf(u0.z); va[3] = f2bf(u0.w);
            va[4] = f2bf(u1.x); va[5] = f2bf(u1.y); va[6] = f2bf(u1.z); va[7] = f2bf(u1.w);
            vb[0] = f2bf(u2.x); vb[1] = f2bf(u2.y); vb[2] = f2bf(u2.z); vb[3] = f2bf(u2.w);
            vb[4] = f2bf(u3.x); vb[5] = f2bf(u3.y); vb[6] = f2bf(u3.z); vb[7] = f2bf(u3.w);
            bf16x8 wa = *(const bf16x8*)(w1bt + (size_t)(col0 + r0c) * C2 + k0 + kc0);
            bf16x8 wb = *(const bf16x8*)(w1bt + (size_t)(col0 + r1c) * C2 + k0 + kc1);
            __syncthreads();
            *(bf16x8*)(&As[r0c][kc0]) = va;
            *(bf16x8*)(&As[r1c][kc1]) = vb;
            *(bf16x8*)(&Bs[r0c][kc0]) = wa;
            *(bf16x8*)(&Bs[r1c][kc1]) = wb;
            __syncthreads();

            bf16x8 af[4], bf[4];
#pragma unroll
            for (int m = 0; m < 4; ++m)
                af[m] = *(const bf16x8*)(&As[wr * 64 + m * 16 + l16][kh]);
#pragma unroll
            for (int n = 0; n < 4; ++n)
                bf[n] = *(const bf16x8*)(&Bs[wc * 64 + n * 16 + l16][kh]);
#pragma unroll
            for (int m = 0; m < 4; ++m)
#pragma unroll
                for (int n = 0; n < 4; ++n)
                    acc[m][n] = __builtin_amdgcn_mfma_f32_16x16x32_bf16(
                        af[m], bf[n], acc[m][n], 0, 0, 0);
        }
#pragma unroll
        for (int n = 0; n < 4; ++n) {
            const int col = col0 + wc * 64 + n * 16 + l16;
#pragma unroll
            for (int m = 0; m < 4; ++m) {
                const int rowb = row0 + wr * 64 + m * 16 + (lane >> 4) * 4;
#pragma unroll
                for (int j = 0; j < 4; ++j)
                    Z[(size_t)(rowb + j) * HID + col] = acc[m][n][j];
            }
        }
        return;
    }

    // ---------------- knn (r13 verbatim; sref in smem) ----------------
    float4* sref = (float4*)smem;            // [N2B + 4], padded: pos = p + p/512
    const int kb = bid - 256;                // 0..1023
    const int qbase = kb * 64;               // 64 queries per block
    const int batch = qbase / N1B;
    const float* k2 = xyz2 + (size_t)batch * N2B * 3;
    for (int p = tid; p < N2B; p += 256) {
        float x = k2[3 * p], y = k2[3 * p + 1], z = k2[3 * p + 2];
        float kk = add_rn(add_rn(mul_rn(x, x), mul_rn(y, y)), mul_rn(z, z));
        sref[p + (p >> 9)] = make_float4(x, y, z, kk);
    }
    __syncthreads();

    const int q = qbase + (tid >> 2);
    const int sub = tid & 3;
    const float qx = xyz1[q * 3 + 0], qy = xyz1[q * 3 + 1], qz = xyz1[q * 3 + 2];
    const float qq = add_rn(add_rn(mul_rn(qx, qx), mul_rn(qy, qy)), mul_rn(qz, qz));

    const int base = sub * 513;              // padded LDS base
    const int gbase = sub * 512;             // global index base
    float a0 = 1e30f, a1 = 1e30f, a2 = 1e30f;
    int   ai0 = 0x7fffffff, ai1 = 0x7fffffff, ai2 = 0x7fffffff;
    float c0 = 1e30f, c1 = 1e30f, c2 = 1e30f;
    int   ci0 = 0x7fffffff, ci1 = 0x7fffffff, ci2 = 0x7fffffff;
    for (int jj = 0; jj < 256; ++jj) {
        float4 rA = sref[base + jj];
        float4 rB = sref[base + 256 + jj];
        float pA = mul_rn(qx, rA.x);
        float tA = fma_rn(qz, rA.z, fma_rn(qy, rA.y, pA));
        float dA = add_rn(sub_rn(qq, add_rn(tA, tA)), rA.w);
        float pB = mul_rn(qx, rB.x);
        float tB = fma_rn(qz, rB.z, fma_rn(qy, rB.y, pB));
        float dB = add_rn(sub_rn(qq, add_rn(tB, tB)), rB.w);
        if (dA < a2) {
            if (dA < a1) {
                a2 = a1; ai2 = ai1;
                if (dA < a0) { a1 = a0; ai1 = ai0; a0 = dA; ai0 = gbase + jj; }
                else         { a1 = dA; ai1 = gbase + jj; }
            } else { a2 = dA; ai2 = gbase + jj; }
        }
        if (dB < c2) {
            if (dB < c1) {
                c2 = c1; ci2 = ci1;
                if (dB < c0) { c1 = c0; ci1 = ci0; c0 = dB; ci0 = gbase + 256 + jj; }
                else         { c1 = dB; ci1 = gbase + 256 + jj; }
            } else { c2 = dB; ci2 = gbase + 256 + jj; }
        }
    }
    float bd0 = a0, bd1 = a1, bd2 = a2;
    int   bi0 = ai0, bi1 = ai1, bi2 = ai2;
#define LEXINS(d, ji)                                                        \
    if ((d < bd2) || (d == bd2 && ji < bi2)) {                               \
        if ((d < bd1) || (d == bd1 && ji < bi1)) {                           \
            bd2 = bd1; bi2 = bi1;                                            \
            if ((d < bd0) || (d == bd0 && ji < bi0)) {                       \
                bd1 = bd0; bi1 = bi0; bd0 = d; bi0 = ji;                     \
            } else { bd1 = d; bi1 = ji; }                                    \
        } else { bd2 = d; bi2 = ji; }                                        \
    }
    LEXINS(c0, ci0) LEXINS(c1, ci1) LEXINS(c2, ci2)
#pragma unroll
    for (int mask = 1; mask <= 2; mask <<= 1) {
        float pd0 = __shfl_xor(bd0, mask, 64);
        float pd1 = __shfl_xor(bd1, mask, 64);
        float pd2 = __shfl_xor(bd2, mask, 64);
        int   pi0 = __shfl_xor(bi0, mask, 64);
        int   pi1 = __shfl_xor(bi1, mask, 64);
        int   pi2 = __shfl_xor(bi2, mask, 64);
        LEXINS(pd0, pi0) LEXINS(pd1, pi1) LEXINS(pd2, pi2)
    }
#undef LEXINS
    if (sub == 0) {
        float d0s = __fsqrt_rn(fmaxf(bd0, 0.0f));
        float d1s = __fsqrt_rn(fmaxf(bd1, 0.0f));
        float d2s = __fsqrt_rn(fmaxf(bd2, 0.0f));
        float r0 = __fdiv_rn(1.0f, add_rn(d0s, 1e-8f));
        float r1 = __fdiv_rn(1.0f, add_rn(d1s, 1e-8f));
        float r2 = __fdiv_rn(1.0f, add_rn(d2s, 1e-8f));
        float rs = add_rn(add_rn(r0, r1), r2);
        w_out[q * 3 + 0] = __fdiv_rn(r0, rs);
        w_out[q * 3 + 1] = __fdiv_rn(r1, rs);
        w_out[q * 3 + 2] = __fdiv_rn(r2, rs);
        idx_out[q * 3 + 0] = batch * N2B + bi0;
        idx_out[q * 3 + 1] = batch * N2B + bi1;
        idx_out[q * 3 + 2] = batch * N2B + bi2;
    }
}

// ============ gemm1m: y1 = P1 @ W1a + IDW(Z) + b1  (8-wave 128x256) ========
__global__ __launch_bounds__(512) void gemm1m_kernel(
    const float* __restrict__ points1, const float* __restrict__ Z,
    const int* __restrict__ idx, const float* __restrict__ w,
    const short* __restrict__ w1at, const float* __restrict__ bias,
    short* __restrict__ y1b, float* __restrict__ psum, float* __restrict__ psq)
{
    __shared__ short As[128][LDP];
    __shared__ short Bs[256][LDP];
    __shared__ int   sidx[128][3];
    __shared__ float swt[128][3];
    __shared__ float redS[2][4][64], redQ[2][4][64];
    const int tid = threadIdx.x;              // 0..511
    const int lane = tid & 63, wv = tid >> 6; // 8 waves
    const int wr = wv >> 2, wc = wv & 3;      // 2 x 4 wave grid (64x64 each)
    const int l16 = lane & 15, kh = (lane >> 4) * 8;
    const int row0 = blockIdx.x * 128;

    if (tid < 128) {
        sidx[tid][0] = idx[(row0 + tid) * 3 + 0];
        sidx[tid][1] = idx[(row0 + tid) * 3 + 1];
        sidx[tid][2] = idx[(row0 + tid) * 3 + 2];
        swt[tid][0] = w[(row0 + tid) * 3 + 0];
        swt[tid][1] = w[(row0 + tid) * 3 + 1];
        swt[tid][2] = w[(row0 + tid) * 3 + 2];
    }

    f32x4 acc[4][4];
#pragma unroll
    for (int m = 0; m < 4; ++m)
#pragma unroll
        for (int n = 0; n < 4; ++n) acc[m][n] = (f32x4){0.f, 0.f, 0.f, 0.f};

    const int arow = tid >> 2, akc = (tid & 3) * 8;
    const int rowA = row0 + arow;
    const int cb0 = tid * 2, cb1 = tid * 2 + 1;
    const int brow0 = cb0 >> 2, bkc0 = (cb0 & 3) * 8;
    const int brow1 = cb1 >> 2, bkc1 = (cb1 & 3) * 8;

#define LOAD_A(VA, KT)                                                        \
    {                                                                         \
        const int k0_ = (KT) * 32;                                            \
        float4 u0 = *(const float4*)(points1 + (size_t)rowA * C1 + k0_ + akc);     \
        float4 u1 = *(const float4*)(points1 + (size_t)rowA * C1 + k0_ + akc + 4); \
        VA[0] = f2bf(u0.x); VA[1] = f2bf(u0.y); VA[2] = f2bf(u0.z); VA[3] = f2bf(u0.w); \
        VA[4] = f2bf(u1.x); VA[5] = f2bf(u1.y); VA[6] = f2bf(u1.z); VA[7] = f2bf(u1.w); \
    }
#define LOAD_B(WA, WB, KT)                                                    \
    {                                                                         \
        const int k0_ = (KT) * 32;                                            \
        WA = *(const bf16x8*)(w1at + (size_t)brow0 * C1 + k0_ + bkc0);        \
        WB = *(const bf16x8*)(w1at + (size_t)brow1 * C1 + k0_ + bkc1);        \
    }

    bf16x8 va, wa, wb;
    LOAD_A(va, 0)
    LOAD_B(wa, wb, 0)
    for (int kt = 0; kt < C1 / 32; ++kt) {
        __syncthreads();
        *(bf16x8*)(&As[arow][akc]) = va;
        *(bf16x8*)(&Bs[brow0][bkc0]) = wa;
        *(bf16x8*)(&Bs[brow1][bkc1]) = wb;
        __syncthreads();
        if (kt + 1 < C1 / 32) {
            LOAD_A(va, kt + 1)
            LOAD_B(wa, wb, kt + 1)
        }
        bf16x8 af[4], bf[4];
#pragma unroll
        for (int m = 0; m < 4; ++m)
            af[m] = *(const bf16x8*)(&As[wr * 64 + m * 16 + l16][kh]);
#pragma unroll
        for (int n = 0; n < 4; ++n)
            bf[n] = *(const bf16x8*)(&Bs[wc * 64 + n * 16 + l16][kh]);
#pragma unroll
        for (int m = 0; m < 4; ++m)
#pragma unroll
            for (int n = 0; n < 4; ++n)
                acc[m][n] = __builtin_amdgcn_mfma_f32_16x16x32_bf16(
                    af[m], bf[n], acc[m][n], 0, 0, 0);
    }
#undef LOAD_A
#undef LOAD_B
    float bv[4];
#pragma unroll
    for (int n = 0; n < 4; ++n) bv[n] = bias[wc * 64 + n * 16 + l16];
    float s[4] = {0.f, 0.f, 0.f, 0.f}, qa[4] = {0.f, 0.f, 0.f, 0.f};
#pragma unroll
    for (int m = 0; m < 4; ++m) {
        const int rl0 = wr * 64 + m * 16 + (lane >> 4) * 4;
#pragma unroll
        for (int j = 0; j < 4; ++j) {
            const int rl = rl0 + j;
            const int j0 = sidx[rl][0], j1 = sidx[rl][1], j2 = sidx[rl][2];
            const float w0 = swt[rl][0], w1 = swt[rl][1], w2 = swt[rl][2];
            const float* z0 = Z + (size_t)j0 * HID;
            const float* z1 = Z + (size_t)j1 * HID;
            const float* z2 = Z + (size_t)j2 * HID;
#pragma unroll
            for (int n = 0; n < 4; ++n) {
                const int col = wc * 64 + n * 16 + l16;
                float zi = fmaf(w0, z0[col], fmaf(w1, z1[col], w2 * z2[col]));
                float v = acc[m][n][j] + bv[n] + zi;
                y1b[(size_t)(row0 + rl) * HID + col] = f2bf(v);
                s[n] += v; qa[n] = fmaf(v, v, qa[n]);
            }
        }
    }
#pragma unroll
    for (int n = 0; n < 4; ++n) {
        float sv = s[n], qv = qa[n];
        sv += __shfl_xor(sv, 16, 64);  sv += __shfl_xor(sv, 32, 64);
        qv += __shfl_xor(qv, 16, 64);  qv += __shfl_xor(qv, 32, 64);
        if ((lane >> 4) == 0) {
            redS[wr][wc][n * 16 + l16] = sv;
            redQ[wr][wc][n * 16 + l16] = qv;
        }
    }
    __syncthreads();
    if (tid < 256) {
        const int wcf = tid >> 6, cf = tid & 63;
        float sv = redS[0][wcf][cf] + redS[1][wcf][cf];
        float qv = redQ[0][wcf][cf] + redQ[1][wcf][cf];
        psum[(size_t)blockIdx.x * HID + tid] = sv;
        psq[(size_t)blockIdx.x * HID + tid] = qv;
    }
}

// ============ gemm2m: 128x128, 4 waves (unchanged) ==========================
#define GEMM_EPILOGUE(STORE_STMT)                                             \
    __shared__ float redS[2][2][64], redQ[2][2][64];                          \
    _Pragma("unroll")                                                         \
    for (int n = 0; n < 4; ++n) {                                             \
        const int col = col0 + wc * 64 + n * 16 + l16;                        \
        const float bv = bias[col];                                           \
        float s = 0.f, qa = 0.f;                                              \
        _Pragma("unroll")                                                     \
        for (int m = 0; m < 4; ++m) {                                         \
            const int rowb = row0 + wr * 64 + m * 16 + (lane >> 4) * 4;       \
            _Pragma("unroll")                                                 \
            for (int j = 0; j < 4; ++j) {                                     \
                float v = acc[m][n][j] + bv;                                  \
                STORE_STMT;                                                   \
                s += v; qa = fmaf(v, v, qa);                                  \
            }                                                                 \
        }                                                                     \
        s += __shfl_xor(s, 16, 64);  s += __shfl_xor(s, 32, 64);              \
        qa += __shfl_xor(qa, 16, 64); qa += __shfl_xor(qa, 32, 64);           \
        if ((lane >> 4) == 0) {                                               \
            redS[wr][wc][n * 16 + l16] = s;                                   \
            redQ[wr][wc][n * 16 + l16] = qa;                                  \
        }                                                                     \
    }                                                                         \
    __syncthreads();                                                          \
    if (tid < 128) {                                                          \
        const int wcf = tid >> 6, cf = tid & 63;                              \
        float s = redS[0][wcf][cf] + redS[1][wcf][cf];                        \
        float qa = redQ[0][wcf][cf] + redQ[1][wcf][cf];                       \
        const int gcol = col0 + wcf * 64 + cf;                                \
        psum[(size_t)blockIdx.y * HID + gcol] = s;                            \
        psq[(size_t)blockIdx.y * HID + gcol] = qa;                            \
    }

__global__ __launch_bounds__(256) void gemm2m_kernel(
    const short* __restrict__ y1b, const float* __restrict__ scale,
    const float* __restrict__ shift, const short* __restrict__ w2t,
    const float* __restrict__ bias, short* __restrict__ y2b,
    float* __restrict__ psum, float* __restrict__ psq)
{
    __shared__ short As[128][LDP];
    __shared__ short Bs[128][LDP];
    const int tid = threadIdx.x;
    const int lane = tid & 63, wv = tid >> 6;
    const int wr = wv >> 1, wc = wv & 1;
    const int l16 = lane & 15, kh = (lane >> 4) * 8;
    const int row0 = blockIdx.y * 128, col0 = blockIdx.x * 128;
    f32x4 acc[4][4];
#pragma unroll
    for (int m = 0; m < 4; ++m)
#pragma unroll
        for (int n = 0; n < 4; ++n) acc[m][n] = (f32x4){0.f, 0.f, 0.f, 0.f};

    const int c0 = tid * 2;
    const int r0c = c0 >> 2, kc0 = (c0 & 3) * 8;
    const int r1c = (c0 + 1) >> 2, kc1 = ((c0 + 1) & 3) * 8;

    for (int kt = 0; kt < HID / 32; ++kt) {
        const int k0 = kt * 32;
        bf16x8 x0 = *(const bf16x8*)(y1b + (size_t)(row0 + r0c) * HID + k0 + kc0);
        bf16x8 x1 = *(const bf16x8*)(y1b + (size_t)(row0 + r1c) * HID + k0 + kc1);
        float4 s0 = *(const float4*)(scale + k0 + kc0);
        float4 s1 = *(const float4*)(scale + k0 + kc0 + 4);
        float4 h0 = *(const float4*)(shift + k0 + kc0);
        float4 h1 = *(const float4*)(shift + k0 + kc0 + 4);
        float4 s2 = *(const float4*)(scale + k0 + kc1);
        float4 s3 = *(const float4*)(scale + k0 + kc1 + 4);
        float4 h2 = *(const float4*)(shift + k0 + kc1);
        float4 h3 = *(const float4*)(shift + k0 + kc1 + 4);
        bf16x8 va, vb;
        va[0] = f2bf(fmaxf(fmaf(bf2f(x0[0]), s0.x, h0.x), 0.f));
        va[1] = f2bf(fmaxf(fmaf(bf2f(x0[1]), s0.y, h0.y), 0.f));
        va[2] = f2bf(fmaxf(fmaf(bf2f(x0[2]), s0.z, h0.z), 0.f));
        va[3] = f2bf(fmaxf(fmaf(bf2f(x0[3]), s0.w, h0.w), 0.f));
        va[4] = f2bf(fmaxf(fmaf(bf2f(x0[4]), s1.x, h1.x), 0.f));
        va[5] = f2bf(fmaxf(fmaf(bf2f(x0[5]), s1.y, h1.y), 0.f));
        va[6] = f2bf(fmaxf(fmaf(bf2f(x0[6]), s1.z, h1.z), 0.f));
        va[7] = f2bf(fmaxf(fmaf(bf2f(x0[7]), s1.w, h1.w), 0.f));
        vb[0] = f2bf(fmaxf(fmaf(bf2f(x1[0]), s2.x, h2.x), 0.f));
        vb[1] = f2bf(fmaxf(fmaf(bf2f(x1[1]), s2.y, h2.y), 0.f));
        vb[2] = f2bf(fmaxf(fmaf(bf2f(x1[2]), s2.z, h2.z), 0.f));
        vb[3] = f2bf(fmaxf(fmaf(bf2f(x1[3]), s2.w, h2.w), 0.f));
        vb[4] = f2bf(fmaxf(fmaf(bf2f(x1[4]), s3.x, h3.x), 0.f));
        vb[5] = f2bf(fmaxf(fmaf(bf2f(x1[5]), s3.y, h3.y), 0.f));
        vb[6] = f2bf(fmaxf(fmaf(bf2f(x1[6]), s3.z, h3.z), 0.f));
        vb[7] = f2bf(fmaxf(fmaf(bf2f(x1[7]), s3.w, h3.w), 0.f));
        bf16x8 wa = *(const bf16x8*)(w2t + (size_t)(col0 + r0c) * HID + k0 + kc0);
        bf16x8 wb = *(const bf16x8*)(w2t + (size_t)(col0 + r1c) * HID + k0 + kc1);
        __syncthreads();
        *(bf16x8*)(&As[r0c][kc0]) = va;
        *(bf16x8*)(&As[r1c][kc1]) = vb;
        *(bf16x8*)(&Bs[r0c][kc0]) = wa;
        *(bf16x8*)(&Bs[r1c][kc1]) = wb;
        __syncthreads();

        bf16x8 af[4], bf[4];
#pragma unroll
        for (int m = 0; m < 4; ++m)
            af[m] = *(const bf16x8*)(&As[wr * 64 + m * 16 + l16][kh]);
#pragma unroll
        for (int n = 0; n < 4; ++n)
            bf[n] = *(const bf16x8*)(&Bs[wc * 64 + n * 16 + l16][kh]);
#pragma unroll
        for (int m = 0; m < 4; ++m)
#pragma unroll
            for (int n = 0; n < 4; ++n)
                acc[m][n] = __builtin_amdgcn_mfma_f32_16x16x32_bf16(
                    af[m], bf[n], acc[m][n], 0, 0, 0);
    }
    GEMM_EPILOGUE(y2b[(size_t)(rowb + j) * HID + col] = f2bf(v))
}

// ----------------------------------------------------- BN finalize (512 rows)
__global__ __launch_bounds__(256) void bn_finalize_kernel(
    const float* __restrict__ psum, const float* __restrict__ psq,
    const float* __restrict__ g, const float* __restrict__ be,
    float* __restrict__ scale, float* __restrict__ shift)
{
    const int c = threadIdx.x;
    float s = 0.0f, q = 0.0f;
    for (int b = 0; b < 512; ++b) { s += psum[b * HID + c]; q += psq[b * HID + c]; }
    const float inv_n = 1.0f / (float)N1T;
    const float mu = s * inv_n;
    const float var = fmaxf(q * inv_n - mu * mu, 0.0f);
    const float sc = g[c] * rsqrtf(var + BN_EPS);
    scale[c] = sc;
    shift[c] = be[c] - mu * sc;
}

// --------------------------------------------------------- final BN+ReLU
__global__ __launch_bounds__(256) void bn_apply_kernel(
    const short* __restrict__ y2b, const float* __restrict__ scale,
    const float* __restrict__ shift, float* __restrict__ out)
{
    const size_t i = ((size_t)blockIdx.x * 256 + threadIdx.x) * 8;
    const int c8 = (int)(i & 255);
    bf16x8 x = *(const bf16x8*)(y2b + i);
    float4 s0 = *(const float4*)(scale + c8);
    float4 s1 = *(const float4*)(scale + c8 + 4);
    float4 h0 = *(const float4*)(shift + c8);
    float4 h1 = *(const float4*)(shift + c8 + 4);
    float4 o0, o1;
    o0.x = fmaxf(fmaf(bf2f(x[0]), s0.x, h0.x), 0.f);
    o0.y = fmaxf(fmaf(bf2f(x[1]), s0.y, h0.y), 0.f);
    o0.z = fmaxf(fmaf(bf2f(x[2]), s0.z, h0.z), 0.f);
    o0.w = fmaxf(fmaf(bf2f(x[3]), s0.w, h0.w), 0.f);
    o1.x = fmaxf(fmaf(bf2f(x[4]), s1.x, h1.x), 0.f);
    o1.y = fmaxf(fmaf(bf2f(x[5]), s1.y, h1.y), 0.f);
    o1.z = fmaxf(fmaf(bf2f(x[6]), s1.z, h1.z), 0.f);
    o1.w = fmaxf(fmaf(bf2f(x[7]), s1.w, h1.w), 0.f);
    *(float4*)(out + i) = o0;
    *(float4*)(out + i + 4) = o1;
}

// -------------------------------------------------------------- launcher
extern "C" void kernel_launch(void* const* d_in, const int* in_sizes, int n_in,
                              void* d_out, int out_size, void* d_ws, size_t ws_size,
                              hipStream_t stream)
{
    const float* xyz1    = (const float*)d_in[0];
    const float* points1 = (const float*)d_in[1];
    const float* xyz2    = (const float*)d_in[2];
    const float* points2 = (const float*)d_in[3];
    const float* W1  = (const float*)d_in[6];
    const float* b1  = (const float*)d_in[7];
    const float* g1  = (const float*)d_in[8];
    const float* be1 = (const float*)d_in[9];
    const float* W2  = (const float*)d_in[10];
    const float* b2  = (const float*)d_in[11];
    const float* g2  = (const float*)d_in[12];
    const float* be2 = (const float*)d_in[13];
    float* out = (float*)d_out;

    char* ws = (char*)d_ws;
    short* y1b  = (short*)ws;                          // bf16 [N1][256]
    short* y2b  = (short*)(ws + 33554432);             // bf16 [N1][256]
    float* Z    = (float*)(ws + 67108864);             // f32 [N2T][256]
    size_t off  = 67108864 + 16777216;
    short*  w1at   = (short*)(ws + off);  off += (size_t)C1 * HID * 2;
    short*  w1bt   = (short*)(ws + off);  off += (size_t)C2 * HID * 2;
    short*  w2t    = (short*)(ws + off);  off += (size_t)HID * HID * 2;
    int*    idx    = (int*)(ws + off);    off += (size_t)N1T * 3 * 4;
    float*  w      = (float*)(ws + off);  off += (size_t)N1T * 3 * 4;
    float*  psum   = (float*)(ws + off);  off += 512 * 256 * 4;
    float*  psq    = (float*)(ws + off);  off += 512 * 256 * 4;
    float*  scale1 = (float*)(ws + off);  off += 256 * 4;
    float*  shift1 = (float*)(ws + off);  off += 256 * 4;
    float*  scale2 = (float*)(ws + off);  off += 256 * 4;
    float*  shift2 = (float*)(ws + off);  off += 256 * 4;

    prep_w_kernel<<<1024, 256, 0, stream>>>(W1, W2, w1at, w1bt, w2t);
    phase1_kernel<<<1280, 256, 0, stream>>>(points2, w1bt, Z,
                                            xyz1, xyz2, idx, w);
    gemm1m_kernel<<<N1T / 128, 512, 0, stream>>>(
        points1, Z, idx, w, w1at, b1, y1b, psum, psq);
    bn_finalize_kernel<<<1, 256, 0, stream>>>(psum, psq, g1, be1, scale1, shift1);
    gemm2m_kernel<<<dim3(HID / 128, N1T / 128), 256, 0, stream>>>(
        y1b, scale1, shift1, w2t, b2, y2b, psum, psq);
    bn_finalize_kernel<<<1, 256, 0, stream>>>(psum, psq, g2, be2, scale2, shift2);
    bn_apply_kernel<<<N1T * HID / 8 / 256, 256, 0, stream>>>(y2b, scale2, shift2, out);
}

// Round 20
// 229.037 us; speedup vs baseline: 1.0206x; 1.0063x over previous
//
#include <hip/hip_runtime.h>
#include <math.h>

#define N1T 65536
#define N2T 16384
#define BSZ 8
#define N1B 8192   // points per batch in xyz1
#define N2B 2048   // points per batch in xyz2
#define C1 256
#define C2 512
#define K1 768     // C1 + C2
#define HID 256
#define BN_EPS 1e-5f

typedef short bf16x8 __attribute__((ext_vector_type(8)));
typedef float f32x4 __attribute__((ext_vector_type(4)));

// Exact single-rounded f32 ops via ISA — immune to -ffast-math / contraction.
__device__ __forceinline__ float mul_rn(float a, float b) {
    float r; asm("v_mul_f32 %0, %1, %2" : "=v"(r) : "v"(a), "v"(b)); return r;
}
__device__ __forceinline__ float add_rn(float a, float b) {
    float r; asm("v_add_f32 %0, %1, %2" : "=v"(r) : "v"(a), "v"(b)); return r;
}
__device__ __forceinline__ float sub_rn(float a, float b) {
    float r; asm("v_sub_f32 %0, %1, %2" : "=v"(r) : "v"(a), "v"(b)); return r;
}
__device__ __forceinline__ float fma_rn(float a, float b, float c) {
    float r; asm("v_fma_f32 %0, %1, %2, %3" : "=v"(r) : "v"(a), "v"(b), "v"(c)); return r;
}
// f32 -> bf16 round-to-nearest-even
__device__ __forceinline__ short f2bf(float f) {
    unsigned u = __builtin_bit_cast(unsigned, f);
    u += 0x7fffu + ((u >> 16) & 1u);
    return (short)(u >> 16);
}
// bf16 -> f32 (exact)
__device__ __forceinline__ float bf2f(short s) {
    return __builtin_bit_cast(float, ((unsigned)(unsigned short)s) << 16);
}

#define LDP 40

// ---------------------------------------------------------------- KNN-3
// FROZEN: r13's standalone kernel verbatim (72 µs; merged variant r19
// regressed to 95 via worse codegen — keep standalone, 52 VGPR).
__global__ __launch_bounds__(256) void knn_kernel(
    const float* __restrict__ xyz1, const float* __restrict__ xyz2,
    int* __restrict__ idx_out, float* __restrict__ w_out)
{
    __shared__ float4 sref[N2B + 4];         // padded: pos = p + p/512
    const int tid = threadIdx.x;
    const int qbase = blockIdx.x * 64;       // 1024 blocks x 64 queries
    const int batch = qbase / N1B;
    const float* k2 = xyz2 + (size_t)batch * N2B * 3;
    for (int p = tid; p < N2B; p += 256) {
        float x = k2[3 * p], y = k2[3 * p + 1], z = k2[3 * p + 2];
        float kk = add_rn(add_rn(mul_rn(x, x), mul_rn(y, y)), mul_rn(z, z));
        sref[p + (p >> 9)] = make_float4(x, y, z, kk);
    }
    __syncthreads();

    const int q = qbase + (tid >> 2);
    const int sub = tid & 3;
    const float qx = xyz1[q * 3 + 0], qy = xyz1[q * 3 + 1], qz = xyz1[q * 3 + 2];
    const float qq = add_rn(add_rn(mul_rn(qx, qx), mul_rn(qy, qy)), mul_rn(qz, qz));

    const int base = sub * 513;              // padded LDS base
    const int gbase = sub * 512;             // global index base
    float a0 = 1e30f, a1 = 1e30f, a2 = 1e30f;
    int   ai0 = 0x7fffffff, ai1 = 0x7fffffff, ai2 = 0x7fffffff;
    float c0 = 1e30f, c1 = 1e30f, c2 = 1e30f;
    int   ci0 = 0x7fffffff, ci1 = 0x7fffffff, ci2 = 0x7fffffff;
    for (int jj = 0; jj < 256; ++jj) {
        float4 rA = sref[base + jj];
        float4 rB = sref[base + 256 + jj];
        float pA = mul_rn(qx, rA.x);
        float tA = fma_rn(qz, rA.z, fma_rn(qy, rA.y, pA));
        float dA = add_rn(sub_rn(qq, add_rn(tA, tA)), rA.w);
        float pB = mul_rn(qx, rB.x);
        float tB = fma_rn(qz, rB.z, fma_rn(qy, rB.y, pB));
        float dB = add_rn(sub_rn(qq, add_rn(tB, tB)), rB.w);
        if (dA < a2) {
            if (dA < a1) {
                a2 = a1; ai2 = ai1;
                if (dA < a0) { a1 = a0; ai1 = ai0; a0 = dA; ai0 = gbase + jj; }
                else         { a1 = dA; ai1 = gbase + jj; }
            } else { a2 = dA; ai2 = gbase + jj; }
        }
        if (dB < c2) {
            if (dB < c1) {
                c2 = c1; ci2 = ci1;
                if (dB < c0) { c1 = c0; ci1 = ci0; c0 = dB; ci0 = gbase + 256 + jj; }
                else         { c1 = dB; ci1 = gbase + 256 + jj; }
            } else { c2 = dB; ci2 = gbase + 256 + jj; }
        }
    }
    float bd0 = a0, bd1 = a1, bd2 = a2;
    int   bi0 = ai0, bi1 = ai1, bi2 = ai2;
#define LEXINS(d, ji)                                                        \
    if ((d < bd2) || (d == bd2 && ji < bi2)) {                               \
        if ((d < bd1) || (d == bd1 && ji < bi1)) {                           \
            bd2 = bd1; bi2 = bi1;                                            \
            if ((d < bd0) || (d == bd0 && ji < bi0)) {                       \
                bd1 = bd0; bi1 = bi0; bd0 = d; bi0 = ji;                     \
            } else { bd1 = d; bi1 = ji; }                                    \
        } else { bd2 = d; bi2 = ji; }                                        \
    }
    LEXINS(c0, ci0) LEXINS(c1, ci1) LEXINS(c2, ci2)
#pragma unroll
    for (int mask = 1; mask <= 2; mask <<= 1) {
        float pd0 = __shfl_xor(bd0, mask, 64);
        float pd1 = __shfl_xor(bd1, mask, 64);
        float pd2 = __shfl_xor(bd2, mask, 64);
        int   pi0 = __shfl_xor(bi0, mask, 64);
        int   pi1 = __shfl_xor(bi1, mask, 64);
        int   pi2 = __shfl_xor(bi2, mask, 64);
        LEXINS(pd0, pi0) LEXINS(pd1, pi1) LEXINS(pd2, pi2)
    }
#undef LEXINS
    if (sub == 0) {
        float d0s = __fsqrt_rn(fmaxf(bd0, 0.0f));
        float d1s = __fsqrt_rn(fmaxf(bd1, 0.0f));
        float d2s = __fsqrt_rn(fmaxf(bd2, 0.0f));
        float r0 = __fdiv_rn(1.0f, add_rn(d0s, 1e-8f));
        float r1 = __fdiv_rn(1.0f, add_rn(d1s, 1e-8f));
        float r2 = __fdiv_rn(1.0f, add_rn(d2s, 1e-8f));
        float rs = add_rn(add_rn(r0, r1), r2);
        w_out[q * 3 + 0] = __fdiv_rn(r0, rs);
        w_out[q * 3 + 1] = __fdiv_rn(r1, rs);
        w_out[q * 3 + 2] = __fdiv_rn(r2, rs);
        idx_out[q * 3 + 0] = batch * N2B + bi0;
        idx_out[q * 3 + 1] = batch * N2B + bi1;
        idx_out[q * 3 + 2] = batch * N2B + bi2;
    }
}

// ================= prep: weight transposes (merged) ========================
__global__ __launch_bounds__(256) void prep_w_kernel(
    const float* __restrict__ W1, const float* __restrict__ W2,
    short* __restrict__ w1at, short* __restrict__ w1bt, short* __restrict__ w2t)
{
    const int bid = blockIdx.x;
    if (bid < 768) {
        const int e = bid * 256 + threadIdx.x;       // over 768*256
        const int k = e / HID, n = e % HID;
        short v = f2bf(W1[e]);
        if (k < C1) w1at[(size_t)n * C1 + k] = v;
        else        w1bt[(size_t)n * C2 + (k - C1)] = v;
    } else {
        const int e = (bid - 768) * 256 + threadIdx.x; // over 256*256
        const int k = e / HID, n = e % HID;
        w2t[(size_t)n * HID + k] = f2bf(W2[e]);
    }
}

// ============ zgemm: Z[16384][256] = bf16(points2) @ W1b (standalone) ======
__global__ __launch_bounds__(256) void zgemm_kernel(
    const float* __restrict__ points2, const short* __restrict__ w1bt,
    float* __restrict__ Z)
{
    __shared__ short As[128][LDP];
    __shared__ short Bs[128][LDP];
    const int tid = threadIdx.x;
    const int lane = tid & 63, wv = tid >> 6;
    const int wr = wv >> 1, wc = wv & 1;
    const int l16 = lane & 15, kh = (lane >> 4) * 8;
    const int row0 = blockIdx.y * 128, col0 = blockIdx.x * 128;
    f32x4 acc[4][4];
#pragma unroll
    for (int m = 0; m < 4; ++m)
#pragma unroll
        for (int n = 0; n < 4; ++n) acc[m][n] = (f32x4){0.f, 0.f, 0.f, 0.f};

    const int c0 = tid * 2;
    const int r0c = c0 >> 2, kc0 = (c0 & 3) * 8;
    const int r1c = (c0 + 1) >> 2, kc1 = ((c0 + 1) & 3) * 8;

    for (int kt = 0; kt < C2 / 32; ++kt) {
        const int k0 = kt * 32;
        float4 u0 = *(const float4*)(points2 + (size_t)(row0 + r0c) * C2 + k0 + kc0);
        float4 u1 = *(const float4*)(points2 + (size_t)(row0 + r0c) * C2 + k0 + kc0 + 4);
        float4 u2 = *(const float4*)(points2 + (size_t)(row0 + r1c) * C2 + k0 + kc1);
        float4 u3 = *(const float4*)(points2 + (size_t)(row0 + r1c) * C2 + k0 + kc1 + 4);
        bf16x8 va, vb;
        va[0] = f2bf(u0.x); va[1] = f2bf(u0.y); va[2] = f2bf(u0.z); va[3] = f2bf(u0.w);
        va[4] = f2bf(u1.x); va[5] = f2bf(u1.y); va[6] = f2bf(u1.z); va[7] = f2bf(u1.w);
        vb[0] = f2bf(u2.x); vb[1] = f2bf(u2.y); vb[2] = f2bf(u2.z); vb[3] = f2bf(u2.w);
        vb[4] = f2bf(u3.x); vb[5] = f2bf(u3.y); vb[6] = f2bf(u3.z); vb[7] = f2bf(u3.w);
        bf16x8 wa = *(const bf16x8*)(w1bt + (size_t)(col0 + r0c) * C2 + k0 + kc0);
        bf16x8 wb = *(const bf16x8*)(w1bt + (size_t)(col0 + r1c) * C2 + k0 + kc1);
        __syncthreads();
        *(bf16x8*)(&As[r0c][kc0]) = va;
        *(bf16x8*)(&As[r1c][kc1]) = vb;
        *(bf16x8*)(&Bs[r0c][kc0]) = wa;
        *(bf16x8*)(&Bs[r1c][kc1]) = wb;
        __syncthreads();

        bf16x8 af[4], bf[4];
#pragma unroll
        for (int m = 0; m < 4; ++m)
            af[m] = *(const bf16x8*)(&As[wr * 64 + m * 16 + l16][kh]);
#pragma unroll
        for (int n = 0; n < 4; ++n)
            bf[n] = *(const bf16x8*)(&Bs[wc * 64 + n * 16 + l16][kh]);
#pragma unroll
        for (int m = 0; m < 4; ++m)
#pragma unroll
            for (int n = 0; n < 4; ++n)
                acc[m][n] = __builtin_amdgcn_mfma_f32_16x16x32_bf16(
                    af[m], bf[n], acc[m][n], 0, 0, 0);
    }
#pragma unroll
    for (int n = 0; n < 4; ++n) {
        const int col = col0 + wc * 64 + n * 16 + l16;
#pragma unroll
        for (int m = 0; m < 4; ++m) {
            const int rowb = row0 + wr * 64 + m * 16 + (lane >> 4) * 4;
#pragma unroll
            for (int j = 0; j < 4; ++j)
                Z[(size_t)(rowb + j) * HID + col] = acc[m][n][j];
        }
    }
}

// ============ gemm1m: y1 = P1 @ W1a + IDW(Z) + b1  (8-wave 128x256) ========
__global__ __launch_bounds__(512) void gemm1m_kernel(
    const float* __restrict__ points1, const float* __restrict__ Z,
    const int* __restrict__ idx, const float* __restrict__ w,
    const short* __restrict__ w1at, const float* __restrict__ bias,
    short* __restrict__ y1b, float* __restrict__ psum, float* __restrict__ psq)
{
    __shared__ short As[128][LDP];
    __shared__ short Bs[256][LDP];
    __shared__ int   sidx[128][3];
    __shared__ float swt[128][3];
    __shared__ float redS[2][4][64], redQ[2][4][64];
    const int tid = threadIdx.x;              // 0..511
    const int lane = tid & 63, wv = tid >> 6; // 8 waves
    const int wr = wv >> 2, wc = wv & 3;      // 2 x 4 wave grid (64x64 each)
    const int l16 = lane & 15, kh = (lane >> 4) * 8;
    const int row0 = blockIdx.x * 128;

    if (tid < 128) {
        sidx[tid][0] = idx[(row0 + tid) * 3 + 0];
        sidx[tid][1] = idx[(row0 + tid) * 3 + 1];
        sidx[tid][2] = idx[(row0 + tid) * 3 + 2];
        swt[tid][0] = w[(row0 + tid) * 3 + 0];
        swt[tid][1] = w[(row0 + tid) * 3 + 1];
        swt[tid][2] = w[(row0 + tid) * 3 + 2];
    }

    f32x4 acc[4][4];
#pragma unroll
    for (int m = 0; m < 4; ++m)
#pragma unroll
        for (int n = 0; n < 4; ++n) acc[m][n] = (f32x4){0.f, 0.f, 0.f, 0.f};

    const int arow = tid >> 2, akc = (tid & 3) * 8;
    const int rowA = row0 + arow;
    const int cb0 = tid * 2, cb1 = tid * 2 + 1;
    const int brow0 = cb0 >> 2, bkc0 = (cb0 & 3) * 8;
    const int brow1 = cb1 >> 2, bkc1 = (cb1 & 3) * 8;

#define LOAD_A(VA, KT)                                                        \
    {                                                                         \
        const int k0_ = (KT) * 32;                                            \
        float4 u0 = *(const float4*)(points1 + (size_t)rowA * C1 + k0_ + akc);     \
        float4 u1 = *(const float4*)(points1 + (size_t)rowA * C1 + k0_ + akc + 4); \
        VA[0] = f2bf(u0.x); VA[1] = f2bf(u0.y); VA[2] = f2bf(u0.z); VA[3] = f2bf(u0.w); \
        VA[4] = f2bf(u1.x); VA[5] = f2bf(u1.y); VA[6] = f2bf(u1.z); VA[7] = f2bf(u1.w); \
    }
#define LOAD_B(WA, WB, KT)                                                    \
    {                                                                         \
        const int k0_ = (KT) * 32;                                            \
        WA = *(const bf16x8*)(w1at + (size_t)brow0 * C1 + k0_ + bkc0);        \
        WB = *(const bf16x8*)(w1at + (size_t)brow1 * C1 + k0_ + bkc1);        \
    }

    bf16x8 va, wa, wb;
    LOAD_A(va, 0)
    LOAD_B(wa, wb, 0)
    for (int kt = 0; kt < C1 / 32; ++kt) {
        __syncthreads();
        *(bf16x8*)(&As[arow][akc]) = va;
        *(bf16x8*)(&Bs[brow0][bkc0]) = wa;
        *(bf16x8*)(&Bs[brow1][bkc1]) = wb;
        __syncthreads();
        if (kt + 1 < C1 / 32) {
            LOAD_A(va, kt + 1)
            LOAD_B(wa, wb, kt + 1)
        }
        bf16x8 af[4], bf[4];
#pragma unroll
        for (int m = 0; m < 4; ++m)
            af[m] = *(const bf16x8*)(&As[wr * 64 + m * 16 + l16][kh]);
#pragma unroll
        for (int n = 0; n < 4; ++n)
            bf[n] = *(const bf16x8*)(&Bs[wc * 64 + n * 16 + l16][kh]);
#pragma unroll
        for (int m = 0; m < 4; ++m)
#pragma unroll
            for (int n = 0; n < 4; ++n)
                acc[m][n] = __builtin_amdgcn_mfma_f32_16x16x32_bf16(
                    af[m], bf[n], acc[m][n], 0, 0, 0);
    }
#undef LOAD_A
#undef LOAD_B
    float bv[4];
#pragma unroll
    for (int n = 0; n < 4; ++n) bv[n] = bias[wc * 64 + n * 16 + l16];
    float s[4] = {0.f, 0.f, 0.f, 0.f}, qa[4] = {0.f, 0.f, 0.f, 0.f};
#pragma unroll
    for (int m = 0; m < 4; ++m) {
        const int rl0 = wr * 64 + m * 16 + (lane >> 4) * 4;
#pragma unroll
        for (int j = 0; j < 4; ++j) {
            const int rl = rl0 + j;
            const int j0 = sidx[rl][0], j1 = sidx[rl][1], j2 = sidx[rl][2];
            const float w0 = swt[rl][0], w1 = swt[rl][1], w2 = swt[rl][2];
            const float* z0 = Z + (size_t)j0 * HID;
            const float* z1 = Z + (size_t)j1 * HID;
            const float* z2 = Z + (size_t)j2 * HID;
#pragma unroll
            for (int n = 0; n < 4; ++n) {
                const int col = wc * 64 + n * 16 + l16;
                float zi = fmaf(w0, z0[col], fmaf(w1, z1[col], w2 * z2[col]));
                float v = acc[m][n][j] + bv[n] + zi;
                y1b[(size_t)(row0 + rl) * HID + col] = f2bf(v);
                s[n] += v; qa[n] = fmaf(v, v, qa[n]);
            }
        }
    }
#pragma unroll
    for (int n = 0; n < 4; ++n) {
        float sv = s[n], qv = qa[n];
        sv += __shfl_xor(sv, 16, 64);  sv += __shfl_xor(sv, 32, 64);
        qv += __shfl_xor(qv, 16, 64);  qv += __shfl_xor(qv, 32, 64);
        if ((lane >> 4) == 0) {
            redS[wr][wc][n * 16 + l16] = sv;
            redQ[wr][wc][n * 16 + l16] = qv;
        }
    }
    __syncthreads();
    if (tid < 256) {
        const int wcf = tid >> 6, cf = tid & 63;
        float sv = redS[0][wcf][cf] + redS[1][wcf][cf];
        float qv = redQ[0][wcf][cf] + redQ[1][wcf][cf];
        psum[(size_t)blockIdx.x * HID + tid] = sv;
        psq[(size_t)blockIdx.x * HID + tid] = qv;
    }
}

// ============ gemm2m: 128x128, 4 waves (unchanged) ==========================
#define GEMM_EPILOGUE(STORE_STMT)                                             \
    __shared__ float redS[2][2][64], redQ[2][2][64];                          \
    _Pragma("unroll")                                                         \
    for (int n = 0; n < 4; ++n) {                                             \
        const int col = col0 + wc * 64 + n * 16 + l16;                        \
        const float bv = bias[col];                                           \
        float s = 0.f, qa = 0.f;                                              \
        _Pragma("unroll")                                                     \
        for (int m = 0; m < 4; ++m) {                                         \
            const int rowb = row0 + wr * 64 + m * 16 + (lane >> 4) * 4;       \
            _Pragma("unroll")                                                 \
            for (int j = 0; j < 4; ++j) {                                     \
                float v = acc[m][n][j] + bv;                                  \
                STORE_STMT;                                                   \
                s += v; qa = fmaf(v, v, qa);                                  \
            }                                                                 \
        }                                                                     \
        s += __shfl_xor(s, 16, 64);  s += __shfl_xor(s, 32, 64);              \
        qa += __shfl_xor(qa, 16, 64); qa += __shfl_xor(qa, 32, 64);           \
        if ((lane >> 4) == 0) {                                               \
            redS[wr][wc][n * 16 + l16] = s;                                   \
            redQ[wr][wc][n * 16 + l16] = qa;                                  \
        }                                                                     \
    }                                                                         \
    __syncthreads();                                                          \
    if (tid < 128) {                                                          \
        const int wcf = tid >> 6, cf = tid & 63;                              \
        float s = redS[0][wcf][cf] + redS[1][wcf][cf];                        \
        float qa = redQ[0][wcf][cf] + redQ[1][wcf][cf];                       \
        const int gcol = col0 + wcf * 64 + cf;                                \
        psum[(size_t)blockIdx.y * HID + gcol] = s;                            \
        psq[(size_t)blockIdx.y * HID + gcol] = qa;                            \
    }

__global__ __launch_bounds__(256) void gemm2m_kernel(
    const short* __restrict__ y1b, const float* __restrict__ scale,
    const float* __restrict__ shift, const short* __restrict__ w2t,
    const float* __restrict__ bias, short* __restrict__ y2b,
    float* __restrict__ psum, float* __restrict__ psq)
{
    __shared__ short As[128][LDP];
    __shared__ short Bs[128][LDP];
    const int tid = threadIdx.x;
    const int lane = tid & 63, wv = tid >> 6;
    const int wr = wv >> 1, wc = wv & 1;
    const int l16 = lane & 15, kh = (lane >> 4) * 8;
    const int row0 = blockIdx.y * 128, col0 = blockIdx.x * 128;
    f32x4 acc[4][4];
#pragma unroll
    for (int m = 0; m < 4; ++m)
#pragma unroll
        for (int n = 0; n < 4; ++n) acc[m][n] = (f32x4){0.f, 0.f, 0.f, 0.f};

    const int c0 = tid * 2;
    const int r0c = c0 >> 2, kc0 = (c0 & 3) * 8;
    const int r1c = (c0 + 1) >> 2, kc1 = ((c0 + 1) & 3) * 8;

    for (int kt = 0; kt < HID / 32; ++kt) {
        const int k0 = kt * 32;
        bf16x8 x0 = *(const bf16x8*)(y1b + (size_t)(row0 + r0c) * HID + k0 + kc0);
        bf16x8 x1 = *(const bf16x8*)(y1b + (size_t)(row0 + r1c) * HID + k0 + kc1);
        float4 s0 = *(const float4*)(scale + k0 + kc0);
        float4 s1 = *(const float4*)(scale + k0 + kc0 + 4);
        float4 h0 = *(const float4*)(shift + k0 + kc0);
        float4 h1 = *(const float4*)(shift + k0 + kc0 + 4);
        float4 s2 = *(const float4*)(scale + k0 + kc1);
        float4 s3 = *(const float4*)(scale + k0 + kc1 + 4);
        float4 h2 = *(const float4*)(shift + k0 + kc1);
        float4 h3 = *(const float4*)(shift + k0 + kc1 + 4);
        bf16x8 va, vb;
        va[0] = f2bf(fmaxf(fmaf(bf2f(x0[0]), s0.x, h0.x), 0.f));
        va[1] = f2bf(fmaxf(fmaf(bf2f(x0[1]), s0.y, h0.y), 0.f));
        va[2] = f2bf(fmaxf(fmaf(bf2f(x0[2]), s0.z, h0.z), 0.f));
        va[3] = f2bf(fmaxf(fmaf(bf2f(x0[3]), s0.w, h0.w), 0.f));
        va[4] = f2bf(fmaxf(fmaf(bf2f(x0[4]), s1.x, h1.x), 0.f));
        va[5] = f2bf(fmaxf(fmaf(bf2f(x0[5]), s1.y, h1.y), 0.f));
        va[6] = f2bf(fmaxf(fmaf(bf2f(x0[6]), s1.z, h1.z), 0.f));
        va[7] = f2bf(fmaxf(fmaf(bf2f(x0[7]), s1.w, h1.w), 0.f));
        vb[0] = f2bf(fmaxf(fmaf(bf2f(x1[0]), s2.x, h2.x), 0.f));
        vb[1] = f2bf(fmaxf(fmaf(bf2f(x1[1]), s2.y, h2.y), 0.f));
        vb[2] = f2bf(fmaxf(fmaf(bf2f(x1[2]), s2.z, h2.z), 0.f));
        vb[3] = f2bf(fmaxf(fmaf(bf2f(x1[3]), s2.w, h2.w), 0.f));
        vb[4] = f2bf(fmaxf(fmaf(bf2f(x1[4]), s3.x, h3.x), 0.f));
        vb[5] = f2bf(fmaxf(fmaf(bf2f(x1[5]), s3.y, h3.y), 0.f));
        vb[6] = f2bf(fmaxf(fmaf(bf2f(x1[6]), s3.z, h3.z), 0.f));
        vb[7] = f2bf(fmaxf(fmaf(bf2f(x1[7]), s3.w, h3.w), 0.f));
        bf16x8 wa = *(const bf16x8*)(w2t + (size_t)(col0 + r0c) * HID + k0 + kc0);
        bf16x8 wb = *(const bf16x8*)(w2t + (size_t)(col0 + r1c) * HID + k0 + kc1);
        __syncthreads();
        *(bf16x8*)(&As[r0c][kc0]) = va;
        *(bf16x8*)(&As[r1c][kc1]) = vb;
        *(bf16x8*)(&Bs[r0c][kc0]) = wa;
        *(bf16x8*)(&Bs[r1c][kc1]) = wb;
        __syncthreads();

        bf16x8 af[4], bf[4];
#pragma unroll
        for (int m = 0; m < 4; ++m)
            af[m] = *(const bf16x8*)(&As[wr * 64 + m * 16 + l16][kh]);
#pragma unroll
        for (int n = 0; n < 4; ++n)
            bf[n] = *(const bf16x8*)(&Bs[wc * 64 + n * 16 + l16][kh]);
#pragma unroll
        for (int m = 0; m < 4; ++m)
#pragma unroll
            for (int n = 0; n < 4; ++n)
                acc[m][n] = __builtin_amdgcn_mfma_f32_16x16x32_bf16(
                    af[m], bf[n], acc[m][n], 0, 0, 0);
    }
    GEMM_EPILOGUE(y2b[(size_t)(rowb + j) * HID + col] = f2bf(v))
}

// ----------------------------------------------------- BN finalize (512 rows)
__global__ __launch_bounds__(256) void bn_finalize_kernel(
    const float* __restrict__ psum, const float* __restrict__ psq,
    const float* __restrict__ g, const float* __restrict__ be,
    float* __restrict__ scale, float* __restrict__ shift)
{
    const int c = threadIdx.x;
    float s = 0.0f, q = 0.0f;
    for (int b = 0; b < 512; ++b) { s += psum[b * HID + c]; q += psq[b * HID + c]; }
    const float inv_n = 1.0f / (float)N1T;
    const float mu = s * inv_n;
    const float var = fmaxf(q * inv_n - mu * mu, 0.0f);
    const float sc = g[c] * rsqrtf(var + BN_EPS);
    scale[c] = sc;
    shift[c] = be[c] - mu * sc;
}

// --------------------------------------------------------- final BN+ReLU
__global__ __launch_bounds__(256) void bn_apply_kernel(
    const short* __restrict__ y2b, const float* __restrict__ scale,
    const float* __restrict__ shift, float* __restrict__ out)
{
    const size_t i = ((size_t)blockIdx.x * 256 + threadIdx.x) * 8;
    const int c8 = (int)(i & 255);
    bf16x8 x = *(const bf16x8*)(y2b + i);
    float4 s0 = *(const float4*)(scale + c8);
    float4 s1 = *(const float4*)(scale + c8 + 4);
    float4 h0 = *(const float4*)(shift + c8);
    float4 h1 = *(const float4*)(shift + c8 + 4);
    float4 o0, o1;
    o0.x = fmaxf(fmaf(bf2f(x[0]), s0.x, h0.x), 0.f);
    o0.y = fmaxf(fmaf(bf2f(x[1]), s0.y, h0.y), 0.f);
    o0.z = fmaxf(fmaf(bf2f(x[2]), s0.z, h0.z), 0.f);
    o0.w = fmaxf(fmaf(bf2f(x[3]), s0.w, h0.w), 0.f);
    o1.x = fmaxf(fmaf(bf2f(x[4]), s1.x, h1.x), 0.f);
    o1.y = fmaxf(fmaf(bf2f(x[5]), s1.y, h1.y), 0.f);
    o1.z = fmaxf(fmaf(bf2f(x[6]), s1.z, h1.z), 0.f);
    o1.w = fmaxf(fmaf(bf2f(x[7]), s1.w, h1.w), 0.f);
    *(float4*)(out + i) = o0;
    *(float4*)(out + i + 4) = o1;
}

// -------------------------------------------------------------- launcher
extern "C" void kernel_launch(void* const* d_in, const int* in_sizes, int n_in,
                              void* d_out, int out_size, void* d_ws, size_t ws_size,
                              hipStream_t stream)
{
    const float* xyz1    = (const float*)d_in[0];
    const float* points1 = (const float*)d_in[1];
    const float* xyz2    = (const float*)d_in[2];
    const float* points2 = (const float*)d_in[3];
    const float* W1  = (const float*)d_in[6];
    const float* b1  = (const float*)d_in[7];
    const float* g1  = (const float*)d_in[8];
    const float* be1 = (const float*)d_in[9];
    const float* W2  = (const float*)d_in[10];
    const float* b2  = (const float*)d_in[11];
    const float* g2  = (const float*)d_in[12];
    const float* be2 = (const float*)d_in[13];
    float* out = (float*)d_out;

    char* ws = (char*)d_ws;
    short* y1b  = (short*)ws;                          // bf16 [N1][256]
    short* y2b  = (short*)(ws + 33554432);             // bf16 [N1][256]
    float* Z    = (float*)(ws + 67108864);             // f32 [N2T][256]
    size_t off  = 67108864 + 16777216;
    short*  w1at   = (short*)(ws + off);  off += (size_t)C1 * HID * 2;
    short*  w1bt   = (short*)(ws + off);  off += (size_t)C2 * HID * 2;
    short*  w2t    = (short*)(ws + off);  off += (size_t)HID * HID * 2;
    int*    idx    = (int*)(ws + off);    off += (size_t)N1T * 3 * 4;
    float*  w      = (float*)(ws + off);  off += (size_t)N1T * 3 * 4;
    float*  psum   = (float*)(ws + off);  off += 512 * 256 * 4;
    float*  psq    = (float*)(ws + off);  off += 512 * 256 * 4;
    float*  scale1 = (float*)(ws + off);  off += 256 * 4;
    float*  shift1 = (float*)(ws + off);  off += 256 * 4;
    float*  scale2 = (float*)(ws + off);  off += 256 * 4;
    float*  shift2 = (float*)(ws + off);  off += 256 * 4;

    prep_w_kernel<<<1024, 256, 0, stream>>>(W1, W2, w1at, w1bt, w2t);
    zgemm_kernel<<<dim3(HID / 128, N2T / 128), 256, 0, stream>>>(points2, w1bt, Z);
    knn_kernel<<<1024, 256, 0, stream>>>(xyz1, xyz2, idx, w);
    gemm1m_kernel<<<N1T / 128, 512, 0, stream>>>(
        points1, Z, idx, w, w1at, b1, y1b, psum, psq);
    bn_finalize_kernel<<<1, 256, 0, stream>>>(psum, psq, g1, be1, scale1, shift1);
    gemm2m_kernel<<<dim3(HID / 128, N1T / 128), 256, 0, stream>>>(
        y1b, scale1, shift1, w2t, b2, y2b, psum, psq);
    bn_finalize_kernel<<<1, 256, 0, stream>>>(psum, psq, g2, be2, scale2, shift2);
    bn_apply_kernel<<<N1T * HID / 8 / 256, 256, 0, stream>>>(y2b, scale2, shift2, out);
}

// Round 21
// 226.284 us; speedup vs baseline: 1.0330x; 1.0122x over previous
//
#include <hip/hip_runtime.h>
#include <math.h>

#define N1T 65536
#define N2T 16384
#define BSZ 8
#define N1B 8192   // points per batch in xyz1
#define N2B 2048   // points per batch in xyz2
#define C1 256
#define C2 512
#define K1 768     // C1 + C2
#define HID 256
#define BN_EPS 1e-5f

typedef short bf16x8 __attribute__((ext_vector_type(8)));
typedef float f32x4 __attribute__((ext_vector_type(4)));

// Exact single-rounded f32 ops via ISA — immune to -ffast-math / contraction.
__device__ __forceinline__ float mul_rn(float a, float b) {
    float r; asm("v_mul_f32 %0, %1, %2" : "=v"(r) : "v"(a), "v"(b)); return r;
}
__device__ __forceinline__ float add_rn(float a, float b) {
    float r; asm("v_add_f32 %0, %1, %2" : "=v"(r) : "v"(a), "v"(b)); return r;
}
__device__ __forceinline__ float sub_rn(float a, float b) {
    float r; asm("v_sub_f32 %0, %1, %2" : "=v"(r) : "v"(a), "v"(b)); return r;
}
__device__ __forceinline__ float fma_rn(float a, float b, float c) {
    float r; asm("v_fma_f32 %0, %1, %2, %3" : "=v"(r) : "v"(a), "v"(b), "v"(c)); return r;
}
// f32 -> bf16 round-to-nearest-even
__device__ __forceinline__ short f2bf(float f) {
    unsigned u = __builtin_bit_cast(unsigned, f);
    u += 0x7fffu + ((u >> 16) & 1u);
    return (short)(u >> 16);
}
// bf16 -> f32 (exact)
__device__ __forceinline__ float bf2f(short s) {
    return __builtin_bit_cast(float, ((unsigned)(unsigned short)s) << 16);
}

#define LDP 40

// ---------------------------------------------------------------- KNN-3
// FROZEN selection semantics (r9/r13). r21: refs stored as (-2x,-2y,-2z,kk);
// mul-by-(-2) is IEEE-exact and RN commutes with exact scaling, so
//   dt2 = fma(qz,-2z, fma(qy,-2y, mul(qx,-2x))) == -2*dt  (bit-exact)
//   d   = add(add(qq, dt2), kk) == add(sub(qq, add(dt,dt)), kk)  (bit-exact)
// 5 VALU ops/candidate instead of 6; selection bit-identical.
__global__ __launch_bounds__(256) void knn_kernel(
    const float* __restrict__ xyz1, const float* __restrict__ xyz2,
    int* __restrict__ idx_out, float* __restrict__ w_out)
{
    __shared__ float4 sref[N2B + 4];         // padded: pos = p + p/512
    const int tid = threadIdx.x;
    const int qbase = blockIdx.x * 64;       // 1024 blocks x 64 queries
    const int batch = qbase / N1B;
    const float* k2 = xyz2 + (size_t)batch * N2B * 3;
    for (int p = tid; p < N2B; p += 256) {
        float x = k2[3 * p], y = k2[3 * p + 1], z = k2[3 * p + 2];
        float kk = add_rn(add_rn(mul_rn(x, x), mul_rn(y, y)), mul_rn(z, z));
        sref[p + (p >> 9)] = make_float4(-2.0f * x, -2.0f * y, -2.0f * z, kk);
    }
    __syncthreads();

    const int q = qbase + (tid >> 2);
    const int sub = tid & 3;
    const float qx = xyz1[q * 3 + 0], qy = xyz1[q * 3 + 1], qz = xyz1[q * 3 + 2];
    const float qq = add_rn(add_rn(mul_rn(qx, qx), mul_rn(qy, qy)), mul_rn(qz, qz));

    const int base = sub * 513;              // padded LDS base
    const int gbase = sub * 512;             // global index base
    float a0 = 1e30f, a1 = 1e30f, a2 = 1e30f;
    int   ai0 = 0x7fffffff, ai1 = 0x7fffffff, ai2 = 0x7fffffff;
    float c0 = 1e30f, c1 = 1e30f, c2 = 1e30f;
    int   ci0 = 0x7fffffff, ci1 = 0x7fffffff, ci2 = 0x7fffffff;
    for (int jj = 0; jj < 256; ++jj) {
        float4 rA = sref[base + jj];
        float4 rB = sref[base + 256 + jj];
        float pA = mul_rn(qx, rA.x);
        float tA = fma_rn(qz, rA.z, fma_rn(qy, rA.y, pA));   // == -2*dot
        float dA = add_rn(add_rn(qq, tA), rA.w);
        float pB = mul_rn(qx, rB.x);
        float tB = fma_rn(qz, rB.z, fma_rn(qy, rB.y, pB));
        float dB = add_rn(add_rn(qq, tB), rB.w);
        if (dA < a2) {
            if (dA < a1) {
                a2 = a1; ai2 = ai1;
                if (dA < a0) { a1 = a0; ai1 = ai0; a0 = dA; ai0 = gbase + jj; }
                else         { a1 = dA; ai1 = gbase + jj; }
            } else { a2 = dA; ai2 = gbase + jj; }
        }
        if (dB < c2) {
            if (dB < c1) {
                c2 = c1; ci2 = ci1;
                if (dB < c0) { c1 = c0; ci1 = ci0; c0 = dB; ci0 = gbase + 256 + jj; }
                else         { c1 = dB; ci1 = gbase + 256 + jj; }
            } else { c2 = dB; ci2 = gbase + 256 + jj; }
        }
    }
    float bd0 = a0, bd1 = a1, bd2 = a2;
    int   bi0 = ai0, bi1 = ai1, bi2 = ai2;
#define LEXINS(d, ji)                                                        \
    if ((d < bd2) || (d == bd2 && ji < bi2)) {                               \
        if ((d < bd1) || (d == bd1 && ji < bi1)) {                           \
            bd2 = bd1; bi2 = bi1;                                            \
            if ((d < bd0) || (d == bd0 && ji < bi0)) {                       \
                bd1 = bd0; bi1 = bi0; bd0 = d; bi0 = ji;                     \
            } else { bd1 = d; bi1 = ji; }                                    \
        } else { bd2 = d; bi2 = ji; }                                        \
    }
    LEXINS(c0, ci0) LEXINS(c1, ci1) LEXINS(c2, ci2)
#pragma unroll
    for (int mask = 1; mask <= 2; mask <<= 1) {
        float pd0 = __shfl_xor(bd0, mask, 64);
        float pd1 = __shfl_xor(bd1, mask, 64);
        float pd2 = __shfl_xor(bd2, mask, 64);
        int   pi0 = __shfl_xor(bi0, mask, 64);
        int   pi1 = __shfl_xor(bi1, mask, 64);
        int   pi2 = __shfl_xor(bi2, mask, 64);
        LEXINS(pd0, pi0) LEXINS(pd1, pi1) LEXINS(pd2, pi2)
    }
#undef LEXINS
    if (sub == 0) {
        float d0s = __fsqrt_rn(fmaxf(bd0, 0.0f));
        float d1s = __fsqrt_rn(fmaxf(bd1, 0.0f));
        float d2s = __fsqrt_rn(fmaxf(bd2, 0.0f));
        float r0 = __fdiv_rn(1.0f, add_rn(d0s, 1e-8f));
        float r1 = __fdiv_rn(1.0f, add_rn(d1s, 1e-8f));
        float r2 = __fdiv_rn(1.0f, add_rn(d2s, 1e-8f));
        float rs = add_rn(add_rn(r0, r1), r2);
        w_out[q * 3 + 0] = __fdiv_rn(r0, rs);
        w_out[q * 3 + 1] = __fdiv_rn(r1, rs);
        w_out[q * 3 + 2] = __fdiv_rn(r2, rs);
        idx_out[q * 3 + 0] = batch * N2B + bi0;
        idx_out[q * 3 + 1] = batch * N2B + bi1;
        idx_out[q * 3 + 2] = batch * N2B + bi2;
    }
}

// ================= prep: weight transposes (merged) ========================
__global__ __launch_bounds__(256) void prep_w_kernel(
    const float* __restrict__ W1, const float* __restrict__ W2,
    short* __restrict__ w1at, short* __restrict__ w1bt, short* __restrict__ w2t)
{
    const int bid = blockIdx.x;
    if (bid < 768) {
        const int e = bid * 256 + threadIdx.x;       // over 768*256
        const int k = e / HID, n = e % HID;
        short v = f2bf(W1[e]);
        if (k < C1) w1at[(size_t)n * C1 + k] = v;
        else        w1bt[(size_t)n * C2 + (k - C1)] = v;
    } else {
        const int e = (bid - 768) * 256 + threadIdx.x; // over 256*256
        const int k = e / HID, n = e % HID;
        w2t[(size_t)n * HID + k] = f2bf(W2[e]);
    }
}

// ============ zgemm: Z[16384][256] = bf16(points2) @ W1b (standalone) ======
__global__ __launch_bounds__(256) void zgemm_kernel(
    const float* __restrict__ points2, const short* __restrict__ w1bt,
    float* __restrict__ Z)
{
    __shared__ short As[128][LDP];
    __shared__ short Bs[128][LDP];
    const int tid = threadIdx.x;
    const int lane = tid & 63, wv = tid >> 6;
    const int wr = wv >> 1, wc = wv & 1;
    const int l16 = lane & 15, kh = (lane >> 4) * 8;
    const int row0 = blockIdx.y * 128, col0 = blockIdx.x * 128;
    f32x4 acc[4][4];
#pragma unroll
    for (int m = 0; m < 4; ++m)
#pragma unroll
        for (int n = 0; n < 4; ++n) acc[m][n] = (f32x4){0.f, 0.f, 0.f, 0.f};

    const int c0 = tid * 2;
    const int r0c = c0 >> 2, kc0 = (c0 & 3) * 8;
    const int r1c = (c0 + 1) >> 2, kc1 = ((c0 + 1) & 3) * 8;

    for (int kt = 0; kt < C2 / 32; ++kt) {
        const int k0 = kt * 32;
        float4 u0 = *(const float4*)(points2 + (size_t)(row0 + r0c) * C2 + k0 + kc0);
        float4 u1 = *(const float4*)(points2 + (size_t)(row0 + r0c) * C2 + k0 + kc0 + 4);
        float4 u2 = *(const float4*)(points2 + (size_t)(row0 + r1c) * C2 + k0 + kc1);
        float4 u3 = *(const float4*)(points2 + (size_t)(row0 + r1c) * C2 + k0 + kc1 + 4);
        bf16x8 va, vb;
        va[0] = f2bf(u0.x); va[1] = f2bf(u0.y); va[2] = f2bf(u0.z); va[3] = f2bf(u0.w);
        va[4] = f2bf(u1.x); va[5] = f2bf(u1.y); va[6] = f2bf(u1.z); va[7] = f2bf(u1.w);
        vb[0] = f2bf(u2.x); vb[1] = f2bf(u2.y); vb[2] = f2bf(u2.z); vb[3] = f2bf(u2.w);
        vb[4] = f2bf(u3.x); vb[5] = f2bf(u3.y); vb[6] = f2bf(u3.z); vb[7] = f2bf(u3.w);
        bf16x8 wa = *(const bf16x8*)(w1bt + (size_t)(col0 + r0c) * C2 + k0 + kc0);
        bf16x8 wb = *(const bf16x8*)(w1bt + (size_t)(col0 + r1c) * C2 + k0 + kc1);
        __syncthreads();
        *(bf16x8*)(&As[r0c][kc0]) = va;
        *(bf16x8*)(&As[r1c][kc1]) = vb;
        *(bf16x8*)(&Bs[r0c][kc0]) = wa;
        *(bf16x8*)(&Bs[r1c][kc1]) = wb;
        __syncthreads();

        bf16x8 af[4], bf[4];
#pragma unroll
        for (int m = 0; m < 4; ++m)
            af[m] = *(const bf16x8*)(&As[wr * 64 + m * 16 + l16][kh]);
#pragma unroll
        for (int n = 0; n < 4; ++n)
            bf[n] = *(const bf16x8*)(&Bs[wc * 64 + n * 16 + l16][kh]);
#pragma unroll
        for (int m = 0; m < 4; ++m)
#pragma unroll
            for (int n = 0; n < 4; ++n)
                acc[m][n] = __builtin_amdgcn_mfma_f32_16x16x32_bf16(
                    af[m], bf[n], acc[m][n], 0, 0, 0);
    }
#pragma unroll
    for (int n = 0; n < 4; ++n) {
        const int col = col0 + wc * 64 + n * 16 + l16;
#pragma unroll
        for (int m = 0; m < 4; ++m) {
            const int rowb = row0 + wr * 64 + m * 16 + (lane >> 4) * 4;
#pragma unroll
            for (int j = 0; j < 4; ++j)
                Z[(size_t)(rowb + j) * HID + col] = acc[m][n][j];
        }
    }
}

// ============ gemm1m: y1 = P1 @ W1a + IDW(Z) + b1  (8-wave 128x256) ========
__global__ __launch_bounds__(512) void gemm1m_kernel(
    const float* __restrict__ points1, const float* __restrict__ Z,
    const int* __restrict__ idx, const float* __restrict__ w,
    const short* __restrict__ w1at, const float* __restrict__ bias,
    short* __restrict__ y1b, float* __restrict__ psum, float* __restrict__ psq)
{
    __shared__ short As[128][LDP];
    __shared__ short Bs[256][LDP];
    __shared__ int   sidx[128][3];
    __shared__ float swt[128][3];
    __shared__ float redS[2][4][64], redQ[2][4][64];
    const int tid = threadIdx.x;              // 0..511
    const int lane = tid & 63, wv = tid >> 6; // 8 waves
    const int wr = wv >> 2, wc = wv & 3;      // 2 x 4 wave grid (64x64 each)
    const int l16 = lane & 15, kh = (lane >> 4) * 8;
    const int row0 = blockIdx.x * 128;

    if (tid < 128) {
        sidx[tid][0] = idx[(row0 + tid) * 3 + 0];
        sidx[tid][1] = idx[(row0 + tid) * 3 + 1];
        sidx[tid][2] = idx[(row0 + tid) * 3 + 2];
        swt[tid][0] = w[(row0 + tid) * 3 + 0];
        swt[tid][1] = w[(row0 + tid) * 3 + 1];
        swt[tid][2] = w[(row0 + tid) * 3 + 2];
    }

    f32x4 acc[4][4];
#pragma unroll
    for (int m = 0; m < 4; ++m)
#pragma unroll
        for (int n = 0; n < 4; ++n) acc[m][n] = (f32x4){0.f, 0.f, 0.f, 0.f};

    const int arow = tid >> 2, akc = (tid & 3) * 8;
    const int rowA = row0 + arow;
    const int cb0 = tid * 2, cb1 = tid * 2 + 1;
    const int brow0 = cb0 >> 2, bkc0 = (cb0 & 3) * 8;
    const int brow1 = cb1 >> 2, bkc1 = (cb1 & 3) * 8;

#define LOAD_A(VA, KT)                                                        \
    {                                                                         \
        const int k0_ = (KT) * 32;                                            \
        float4 u0 = *(const float4*)(points1 + (size_t)rowA * C1 + k0_ + akc);     \
        float4 u1 = *(const float4*)(points1 + (size_t)rowA * C1 + k0_ + akc + 4); \
        VA[0] = f2bf(u0.x); VA[1] = f2bf(u0.y); VA[2] = f2bf(u0.z); VA[3] = f2bf(u0.w); \
        VA[4] = f2bf(u1.x); VA[5] = f2bf(u1.y); VA[6] = f2bf(u1.z); VA[7] = f2bf(u1.w); \
    }
#define LOAD_B(WA, WB, KT)                                                    \
    {                                                                         \
        const int k0_ = (KT) * 32;                                            \
        WA = *(const bf16x8*)(w1at + (size_t)brow0 * C1 + k0_ + bkc0);        \
        WB = *(const bf16x8*)(w1at + (size_t)brow1 * C1 + k0_ + bkc1);        \
    }

    bf16x8 va, wa, wb;
    LOAD_A(va, 0)
    LOAD_B(wa, wb, 0)
    for (int kt = 0; kt < C1 / 32; ++kt) {
        __syncthreads();
        *(bf16x8*)(&As[arow][akc]) = va;
        *(bf16x8*)(&Bs[brow0][bkc0]) = wa;
        *(bf16x8*)(&Bs[brow1][bkc1]) = wb;
        __syncthreads();
        if (kt + 1 < C1 / 32) {
            LOAD_A(va, kt + 1)
            LOAD_B(wa, wb, kt + 1)
        }
        bf16x8 af[4], bf[4];
#pragma unroll
        for (int m = 0; m < 4; ++m)
            af[m] = *(const bf16x8*)(&As[wr * 64 + m * 16 + l16][kh]);
#pragma unroll
        for (int n = 0; n < 4; ++n)
            bf[n] = *(const bf16x8*)(&Bs[wc * 64 + n * 16 + l16][kh]);
#pragma unroll
        for (int m = 0; m < 4; ++m)
#pragma unroll
            for (int n = 0; n < 4; ++n)
                acc[m][n] = __builtin_amdgcn_mfma_f32_16x16x32_bf16(
                    af[m], bf[n], acc[m][n], 0, 0, 0);
    }
#undef LOAD_A
#undef LOAD_B
    float bv[4];
#pragma unroll
    for (int n = 0; n < 4; ++n) bv[n] = bias[wc * 64 + n * 16 + l16];
    float s[4] = {0.f, 0.f, 0.f, 0.f}, qa[4] = {0.f, 0.f, 0.f, 0.f};
#pragma unroll
    for (int m = 0; m < 4; ++m) {
        const int rl0 = wr * 64 + m * 16 + (lane >> 4) * 4;
#pragma unroll
        for (int j = 0; j < 4; ++j) {
            const int rl = rl0 + j;
            const int j0 = sidx[rl][0], j1 = sidx[rl][1], j2 = sidx[rl][2];
            const float w0 = swt[rl][0], w1 = swt[rl][1], w2 = swt[rl][2];
            const float* z0 = Z + (size_t)j0 * HID;
            const float* z1 = Z + (size_t)j1 * HID;
            const float* z2 = Z + (size_t)j2 * HID;
#pragma unroll
            for (int n = 0; n < 4; ++n) {
                const int col = wc * 64 + n * 16 + l16;
                float zi = fmaf(w0, z0[col], fmaf(w1, z1[col], w2 * z2[col]));
                float v = acc[m][n][j] + bv[n] + zi;
                y1b[(size_t)(row0 + rl) * HID + col] = f2bf(v);
                s[n] += v; qa[n] = fmaf(v, v, qa[n]);
            }
        }
    }
#pragma unroll
    for (int n = 0; n < 4; ++n) {
        float sv = s[n], qv = qa[n];
        sv += __shfl_xor(sv, 16, 64);  sv += __shfl_xor(sv, 32, 64);
        qv += __shfl_xor(qv, 16, 64);  qv += __shfl_xor(qv, 32, 64);
        if ((lane >> 4) == 0) {
            redS[wr][wc][n * 16 + l16] = sv;
            redQ[wr][wc][n * 16 + l16] = qv;
        }
    }
    __syncthreads();
    if (tid < 256) {
        const int wcf = tid >> 6, cf = tid & 63;
        float sv = redS[0][wcf][cf] + redS[1][wcf][cf];
        float qv = redQ[0][wcf][cf] + redQ[1][wcf][cf];
        psum[(size_t)blockIdx.x * HID + tid] = sv;
        psq[(size_t)blockIdx.x * HID + tid] = qv;
    }
}

// ============ gemm2m: 128x128, 4 waves (unchanged) ==========================
#define GEMM_EPILOGUE(STORE_STMT)                                             \
    __shared__ float redS[2][2][64], redQ[2][2][64];                          \
    _Pragma("unroll")                                                         \
    for (int n = 0; n < 4; ++n) {                                             \
        const int col = col0 + wc * 64 + n * 16 + l16;                        \
        const float bv = bias[col];                                           \
        float s = 0.f, qa = 0.f;                                              \
        _Pragma("unroll")                                                     \
        for (int m = 0; m < 4; ++m) {                                         \
            const int rowb = row0 + wr * 64 + m * 16 + (lane >> 4) * 4;       \
            _Pragma("unroll")                                                 \
            for (int j = 0; j < 4; ++j) {                                     \
                float v = acc[m][n][j] + bv;                                  \
                STORE_STMT;                                                   \
                s += v; qa = fmaf(v, v, qa);                                  \
            }                                                                 \
        }                                                                     \
        s += __shfl_xor(s, 16, 64);  s += __shfl_xor(s, 32, 64);              \
        qa += __shfl_xor(qa, 16, 64); qa += __shfl_xor(qa, 32, 64);           \
        if ((lane >> 4) == 0) {                                               \
            redS[wr][wc][n * 16 + l16] = s;                                   \
            redQ[wr][wc][n * 16 + l16] = qa;                                  \
        }                                                                     \
    }                                                                         \
    __syncthreads();                                                          \
    if (tid < 128) {                                                          \
        const int wcf = tid >> 6, cf = tid & 63;                              \
        float s = redS[0][wcf][cf] + redS[1][wcf][cf];                        \
        float qa = redQ[0][wcf][cf] + redQ[1][wcf][cf];                       \
        const int gcol = col0 + wcf * 64 + cf;                                \
        psum[(size_t)blockIdx.y * HID + gcol] = s;                            \
        psq[(size_t)blockIdx.y * HID + gcol] = qa;                            \
    }

__global__ __launch_bounds__(256) void gemm2m_kernel(
    const short* __restrict__ y1b, const float* __restrict__ scale,
    const float* __restrict__ shift, const short* __restrict__ w2t,
    const float* __restrict__ bias, short* __restrict__ y2b,
    float* __restrict__ psum, float* __restrict__ psq)
{
    __shared__ short As[128][LDP];
    __shared__ short Bs[128][LDP];
    const int tid = threadIdx.x;
    const int lane = tid & 63, wv = tid >> 6;
    const int wr = wv >> 1, wc = wv & 1;
    const int l16 = lane & 15, kh = (lane >> 4) * 8;
    const int row0 = blockIdx.y * 128, col0 = blockIdx.x * 128;
    f32x4 acc[4][4];
#pragma unroll
    for (int m = 0; m < 4; ++m)
#pragma unroll
        for (int n = 0; n < 4; ++n) acc[m][n] = (f32x4){0.f, 0.f, 0.f, 0.f};

    const int c0 = tid * 2;
    const int r0c = c0 >> 2, kc0 = (c0 & 3) * 8;
    const int r1c = (c0 + 1) >> 2, kc1 = ((c0 + 1) & 3) * 8;

    for (int kt = 0; kt < HID / 32; ++kt) {
        const int k0 = kt * 32;
        bf16x8 x0 = *(const bf16x8*)(y1b + (size_t)(row0 + r0c) * HID + k0 + kc0);
        bf16x8 x1 = *(const bf16x8*)(y1b + (size_t)(row0 + r1c) * HID + k0 + kc1);
        float4 s0 = *(const float4*)(scale + k0 + kc0);
        float4 s1 = *(const float4*)(scale + k0 + kc0 + 4);
        float4 h0 = *(const float4*)(shift + k0 + kc0);
        float4 h1 = *(const float4*)(shift + k0 + kc0 + 4);
        float4 s2 = *(const float4*)(scale + k0 + kc1);
        float4 s3 = *(const float4*)(scale + k0 + kc1 + 4);
        float4 h2 = *(const float4*)(shift + k0 + kc1);
        float4 h3 = *(const float4*)(shift + k0 + kc1 + 4);
        bf16x8 va, vb;
        va[0] = f2bf(fmaxf(fmaf(bf2f(x0[0]), s0.x, h0.x), 0.f));
        va[1] = f2bf(fmaxf(fmaf(bf2f(x0[1]), s0.y, h0.y), 0.f));
        va[2] = f2bf(fmaxf(fmaf(bf2f(x0[2]), s0.z, h0.z), 0.f));
        va[3] = f2bf(fmaxf(fmaf(bf2f(x0[3]), s0.w, h0.w), 0.f));
        va[4] = f2bf(fmaxf(fmaf(bf2f(x0[4]), s1.x, h1.x), 0.f));
        va[5] = f2bf(fmaxf(fmaf(bf2f(x0[5]), s1.y, h1.y), 0.f));
        va[6] = f2bf(fmaxf(fmaf(bf2f(x0[6]), s1.z, h1.z), 0.f));
        va[7] = f2bf(fmaxf(fmaf(bf2f(x0[7]), s1.w, h1.w), 0.f));
        vb[0] = f2bf(fmaxf(fmaf(bf2f(x1[0]), s2.x, h2.x), 0.f));
        vb[1] = f2bf(fmaxf(fmaf(bf2f(x1[1]), s2.y, h2.y), 0.f));
        vb[2] = f2bf(fmaxf(fmaf(bf2f(x1[2]), s2.z, h2.z), 0.f));
        vb[3] = f2bf(fmaxf(fmaf(bf2f(x1[3]), s2.w, h2.w), 0.f));
        vb[4] = f2bf(fmaxf(fmaf(bf2f(x1[4]), s3.x, h3.x), 0.f));
        vb[5] = f2bf(fmaxf(fmaf(bf2f(x1[5]), s3.y, h3.y), 0.f));
        vb[6] = f2bf(fmaxf(fmaf(bf2f(x1[6]), s3.z, h3.z), 0.f));
        vb[7] = f2bf(fmaxf(fmaf(bf2f(x1[7]), s3.w, h3.w), 0.f));
        bf16x8 wa = *(const bf16x8*)(w2t + (size_t)(col0 + r0c) * HID + k0 + kc0);
        bf16x8 wb = *(const bf16x8*)(w2t + (size_t)(col0 + r1c) * HID + k0 + kc1);
        __syncthreads();
        *(bf16x8*)(&As[r0c][kc0]) = va;
        *(bf16x8*)(&As[r1c][kc1]) = vb;
        *(bf16x8*)(&Bs[r0c][kc0]) = wa;
        *(bf16x8*)(&Bs[r1c][kc1]) = wb;
        __syncthreads();

        bf16x8 af[4], bf[4];
#pragma unroll
        for (int m = 0; m < 4; ++m)
            af[m] = *(const bf16x8*)(&As[wr * 64 + m * 16 + l16][kh]);
#pragma unroll
        for (int n = 0; n < 4; ++n)
            bf[n] = *(const bf16x8*)(&Bs[wc * 64 + n * 16 + l16][kh]);
#pragma unroll
        for (int m = 0; m < 4; ++m)
#pragma unroll
            for (int n = 0; n < 4; ++n)
                acc[m][n] = __builtin_amdgcn_mfma_f32_16x16x32_bf16(
                    af[m], bf[n], acc[m][n], 0, 0, 0);
    }
    GEMM_EPILOGUE(y2b[(size_t)(rowb + j) * HID + col] = f2bf(v))
}

// ----------------------------------------------------- BN finalize (512 rows)
__global__ __launch_bounds__(256) void bn_finalize_kernel(
    const float* __restrict__ psum, const float* __restrict__ psq,
    const float* __restrict__ g, const float* __restrict__ be,
    float* __restrict__ scale, float* __restrict__ shift)
{
    const int c = threadIdx.x;
    float s = 0.0f, q = 0.0f;
    for (int b = 0; b < 512; ++b) { s += psum[b * HID + c]; q += psq[b * HID + c]; }
    const float inv_n = 1.0f / (float)N1T;
    const float mu = s * inv_n;
    const float var = fmaxf(q * inv_n - mu * mu, 0.0f);
    const float sc = g[c] * rsqrtf(var + BN_EPS);
    scale[c] = sc;
    shift[c] = be[c] - mu * sc;
}

// --------------------------------------------------------- final BN+ReLU
__global__ __launch_bounds__(256) void bn_apply_kernel(
    const short* __restrict__ y2b, const float* __restrict__ scale,
    const float* __restrict__ shift, float* __restrict__ out)
{
    const size_t i = ((size_t)blockIdx.x * 256 + threadIdx.x) * 8;
    const int c8 = (int)(i & 255);
    bf16x8 x = *(const bf16x8*)(y2b + i);
    float4 s0 = *(const float4*)(scale + c8);
    float4 s1 = *(const float4*)(scale + c8 + 4);
    float4 h0 = *(const float4*)(shift + c8);
    float4 h1 = *(const float4*)(shift + c8 + 4);
    float4 o0, o1;
    o0.x = fmaxf(fmaf(bf2f(x[0]), s0.x, h0.x), 0.f);
    o0.y = fmaxf(fmaf(bf2f(x[1]), s0.y, h0.y), 0.f);
    o0.z = fmaxf(fmaf(bf2f(x[2]), s0.z, h0.z), 0.f);
    o0.w = fmaxf(fmaf(bf2f(x[3]), s0.w, h0.w), 0.f);
    o1.x = fmaxf(fmaf(bf2f(x[4]), s1.x, h1.x), 0.f);
    o1.y = fmaxf(fmaf(bf2f(x[5]), s1.y, h1.y), 0.f);
    o1.z = fmaxf(fmaf(bf2f(x[6]), s1.z, h1.z), 0.f);
    o1.w = fmaxf(fmaf(bf2f(x[7]), s1.w, h1.w), 0.f);
    *(float4*)(out + i) = o0;
    *(float4*)(out + i + 4) = o1;
}

// -------------------------------------------------------------- launcher
extern "C" void kernel_launch(void* const* d_in, const int* in_sizes, int n_in,
                              void* d_out, int out_size, void* d_ws, size_t ws_size,
                              hipStream_t stream)
{
    const float* xyz1    = (const float*)d_in[0];
    const float* points1 = (const float*)d_in[1];
    const float* xyz2    = (const float*)d_in[2];
    const float* points2 = (const float*)d_in[3];
    const float* W1  = (const float*)d_in[6];
    const float* b1  = (const float*)d_in[7];
    const float* g1  = (const float*)d_in[8];
    const float* be1 = (const float*)d_in[9];
    const float* W2  = (const float*)d_in[10];
    const float* b2  = (const float*)d_in[11];
    const float* g2  = (const float*)d_in[12];
    const float* be2 = (const float*)d_in[13];
    float* out = (float*)d_out;

    char* ws = (char*)d_ws;
    short* y1b  = (short*)ws;                          // bf16 [N1][256]
    short* y2b  = (short*)(ws + 33554432);             // bf16 [N1][256]
    float* Z    = (float*)(ws + 67108864);             // f32 [N2T][256]
    size_t off  = 67108864 + 16777216;
    short*  w1at   = (short*)(ws + off);  off += (size_t)C1 * HID * 2;
    short*  w1bt   = (short*)(ws + off);  off += (size_t)C2 * HID * 2;
    short*  w2t    = (short*)(ws + off);  off += (size_t)HID * HID * 2;
    int*    idx    = (int*)(ws + off);    off += (size_t)N1T * 3 * 4;
    float*  w      = (float*)(ws + off);  off += (size_t)N1T * 3 * 4;
    float*  psum   = (float*)(ws + off);  off += 512 * 256 * 4;
    float*  psq    = (float*)(ws + off);  off += 512 * 256 * 4;
    float*  scale1 = (float*)(ws + off);  off += 256 * 4;
    float*  shift1 = (float*)(ws + off);  off += 256 * 4;
    float*  scale2 = (float*)(ws + off);  off += 256 * 4;
    float*  shift2 = (float*)(ws + off);  off += 256 * 4;

    prep_w_kernel<<<1024, 256, 0, stream>>>(W1, W2, w1at, w1bt, w2t);
    zgemm_kernel<<<dim3(HID / 128, N2T / 128), 256, 0, stream>>>(points2, w1bt, Z);
    knn_kernel<<<1024, 256, 0, stream>>>(xyz1, xyz2, idx, w);
    gemm1m_kernel<<<N1T / 128, 512, 0, stream>>>(
        points1, Z, idx, w, w1at, b1, y1b, psum, psq);
    bn_finalize_kernel<<<1, 256, 0, stream>>>(psum, psq, g1, be1, scale1, shift1);
    gemm2m_kernel<<<dim3(HID / 128, N1T / 128), 256, 0, stream>>>(
        y1b, scale1, shift1, w2t, b2, y2b, psum, psq);
    bn_finalize_kernel<<<1, 256, 0, stream>>>(psum, psq, g2, be2, scale2, shift2);
    bn_apply_kernel<<<N1T * HID / 8 / 256, 256, 0, stream>>>(y2b, scale2, shift2, out);
}